// Round 1
// baseline (7376.910 us; speedup 1.0000x reference)
//
#include <hip/hip_runtime.h>
#include <math.h>

#define LR_GAT(x) ((x) > 0.f ? (x) : 0.2f * (x))

__device__ inline void atomicMaxF(float* addr, float val) {
  int* ai = (int*)addr;
  int old = __float_as_int(*addr);
  while (val > __int_as_float(old)) {
    int assumed = old;
    old = atomicCAS(ai, assumed, __float_as_int(val));
    if (old == assumed) break;
  }
}

// layer-1 transform: xl = x@Wl, xr = x@Wr ; K <= 16, out dim 256
__global__ void k_lin_small(const float* __restrict__ x, const float* __restrict__ Wl,
                            const float* __restrict__ Wr, int N, int K,
                            float* __restrict__ xl, float* __restrict__ xr) {
  int n = blockIdx.x;
  int j = threadIdx.x;
  __shared__ float xs[16];
  if (j < K) xs[j] = x[(size_t)n * K + j];
  __syncthreads();
  float al = 0.f, ar = 0.f;
  for (int k = 0; k < K; ++k) {
    float xv = xs[k];
    al = fmaf(xv, Wl[k * 256 + j], al);
    ar = fmaf(xv, Wr[k * 256 + j], ar);
  }
  xl[(size_t)n * 256 + j] = al;
  xr[(size_t)n * 256 + j] = ar;
}

__global__ void k_init_ms(float* __restrict__ m, float* __restrict__ s, int n) {
  int i = blockIdx.x * blockDim.x + threadIdx.x;
  if (i < n) { m[i] = -INFINITY; s[i] = 0.f; }
}

// init layer output to broadcast bias (accumulator base)
__global__ void k_init_bias(float* __restrict__ out, const float* __restrict__ b) {
  out[(size_t)blockIdx.x * 256 + threadIdx.x] = b[threadIdx.x];
}

// C[N,256] = A[N,256] @ W[256,256]; 64x64 tile, 4x4 microtile, fp32
__global__ void k_mm256(const float* __restrict__ A, const float* __restrict__ W,
                        float* __restrict__ C, int N) {
  __shared__ float As[16][64];  // [k][m]
  __shared__ float Bs[16][64];  // [k][n]
  const int m0 = blockIdx.x * 64;
  const int n0 = blockIdx.y * 64;
  const int t = threadIdx.x;
  const int tn = (t & 15) * 4;
  const int tm = (t >> 4) * 4;
  const int la_row = t >> 2;        // 0..63
  const int la_kq = (t & 3) * 4;    // 0,4,8,12
  const int lb_k = t >> 4;          // 0..15
  const int lb_n = (t & 15) * 4;    // 0..60
  const int rowA = m0 + la_row;
  float acc[4][4] = {};
  for (int kt = 0; kt < 256; kt += 16) {
    float4 a4 = make_float4(0.f, 0.f, 0.f, 0.f);
    if (rowA < N) a4 = *(const float4*)&A[(size_t)rowA * 256 + kt + la_kq];
    float4 b4 = *(const float4*)&W[(size_t)(kt + lb_k) * 256 + n0 + lb_n];
    __syncthreads();
    As[la_kq + 0][la_row] = a4.x;
    As[la_kq + 1][la_row] = a4.y;
    As[la_kq + 2][la_row] = a4.z;
    As[la_kq + 3][la_row] = a4.w;
    *(float4*)&Bs[lb_k][lb_n] = b4;
    __syncthreads();
#pragma unroll
    for (int k = 0; k < 16; ++k) {
      float4 av = *(const float4*)&As[k][tm];
      float4 bv = *(const float4*)&Bs[k][tn];
      acc[0][0] = fmaf(av.x, bv.x, acc[0][0]);
      acc[0][1] = fmaf(av.x, bv.y, acc[0][1]);
      acc[0][2] = fmaf(av.x, bv.z, acc[0][2]);
      acc[0][3] = fmaf(av.x, bv.w, acc[0][3]);
      acc[1][0] = fmaf(av.y, bv.x, acc[1][0]);
      acc[1][1] = fmaf(av.y, bv.y, acc[1][1]);
      acc[1][2] = fmaf(av.y, bv.z, acc[1][2]);
      acc[1][3] = fmaf(av.y, bv.w, acc[1][3]);
      acc[2][0] = fmaf(av.z, bv.x, acc[2][0]);
      acc[2][1] = fmaf(av.z, bv.y, acc[2][1]);
      acc[2][2] = fmaf(av.z, bv.z, acc[2][2]);
      acc[2][3] = fmaf(av.z, bv.w, acc[2][3]);
      acc[3][0] = fmaf(av.w, bv.x, acc[3][0]);
      acc[3][1] = fmaf(av.w, bv.y, acc[3][1]);
      acc[3][2] = fmaf(av.w, bv.z, acc[3][2]);
      acc[3][3] = fmaf(av.w, bv.w, acc[3][3]);
    }
  }
#pragma unroll
  for (int r = 0; r < 4; ++r) {
    int row = m0 + tm + r;
    if (row < N)
      *(float4*)&C[(size_t)row * 256 + n0 + tn] =
          make_float4(acc[r][0], acc[r][1], acc[r][2], acc[r][3]);
  }
}

// one wave per edge: logit[e,h] = sum_c lrelu(xl[s]+xr[d])*att ; atomicMax m[d,h]
template <int H>
__global__ void k_edge_logits(const float* __restrict__ xl, const float* __restrict__ xr,
                              const int* __restrict__ ei, int E, int N,
                              const float* __restrict__ att,
                              float* __restrict__ lg, float* __restrict__ m) {
  int e = blockIdx.x * 4 + (threadIdx.x >> 6);
  if (e >= E + N) return;
  int lane = threadIdx.x & 63;
  int s_, d_;
  if (e < E) { s_ = ei[e]; d_ = ei[E + e]; } else { s_ = d_ = e - E; }
  float4 a = *(const float4*)&xl[(size_t)s_ * 256 + lane * 4];
  float4 b = *(const float4*)&xr[(size_t)d_ * 256 + lane * 4];
  float4 w = *(const float4*)&att[lane * 4];
  float p = LR_GAT(a.x + b.x) * w.x + LR_GAT(a.y + b.y) * w.y +
            LR_GAT(a.z + b.z) * w.z + LR_GAT(a.w + b.w) * w.w;
#pragma unroll
  for (int off = 1; off <= 16; off <<= 1) p += __shfl_xor(p, off, 64);
  if (H == 1) p += __shfl_xor(p, 32, 64);
  if (lane == 0 || (H == 2 && lane == 32)) {
    int h = (lane == 32) ? 1 : 0;
    lg[(size_t)e * H + h] = p;
    atomicMaxF(&m[d_ * H + h], p);
  }
}

template <int H>
__global__ void k_edge_expsum(const int* __restrict__ ei, int E, int N,
                              const float* __restrict__ m, float* __restrict__ lg,
                              float* __restrict__ s) {
  int idx = blockIdx.x * blockDim.x + threadIdx.x;
  int tot = (E + N) * H;
  if (idx >= tot) return;
  int e = (H == 2) ? (idx >> 1) : idx;
  int h = (H == 2) ? (idx & 1) : 0;
  int d = (e < E) ? ei[E + e] : (e - E);
  float a = expf(lg[idx] - m[d * H + h]);
  lg[idx] = a;
  atomicAdd(&s[d * H + h], a);
}

template <int H>
__global__ void k_edge_scatter(const float* __restrict__ xl, const int* __restrict__ ei,
                               int E, int N, const float* __restrict__ lg,
                               const float* __restrict__ s, float* __restrict__ out) {
  int e = blockIdx.x * 4 + (threadIdx.x >> 6);
  if (e >= E + N) return;
  int lane = threadIdx.x & 63;
  int s_, d_;
  if (e < E) { s_ = ei[e]; d_ = ei[E + e]; } else { s_ = d_ = e - E; }
  int h = (H == 2) ? (lane >> 5) : 0;
  float alpha = lg[(size_t)e * H + h] / s[d_ * H + h];
  float4 a = *(const float4*)&xl[(size_t)s_ * 256 + lane * 4];
  float* o = &out[(size_t)d_ * 256 + lane * 4];
  atomicAdd(o + 0, a.x * alpha);
  atomicAdd(o + 1, a.y * alpha);
  atomicAdd(o + 2, a.z * alpha);
  atomicAdd(o + 3, a.w * alpha);
}

// batch ids are sorted: binary-search the segment, mean over it
__global__ void k_pool(const float* __restrict__ x, const int* __restrict__ batch, int N,
                       float* __restrict__ pool) {
  int b = blockIdx.x;
  int j = threadIdx.x;
  __shared__ int sss, sse;
  if (j == 0) {
    int lo = 0, hi = N;
    while (lo < hi) { int mid = (lo + hi) >> 1; if (batch[mid] < b) lo = mid + 1; else hi = mid; }
    sss = lo;
    lo = 0; hi = N;
    while (lo < hi) { int mid = (lo + hi) >> 1; if (batch[mid] < b + 1) lo = mid + 1; else hi = mid; }
    sse = lo;
  }
  __syncthreads();
  float acc = 0.f;
  for (int n = sss; n < sse; ++n) acc += x[(size_t)n * 256 + j];
  float cnt = (float)(sse - sss);
  pool[b * 256 + j] = acc / fmaxf(cnt, 1.f);
}

// fused head: attn (single-key softmax == 1) -> concat -> fc1 -> LN -> lrelu -> fc2
__global__ void k_head(const float* __restrict__ pp, const float* __restrict__ lp,
                       const float* __restrict__ Wv, const float* __restrict__ bv,
                       const float* __restrict__ Wo, const float* __restrict__ bo,
                       const float* __restrict__ fc1w, const float* __restrict__ fc1b,
                       const float* __restrict__ lng, const float* __restrict__ lnb,
                       const float* __restrict__ fc2w, const float* __restrict__ fc2b,
                       float* __restrict__ out) {
  int b = blockIdx.x;
  int j = threadIdx.x;
  __shared__ float lxs[256];
  __shared__ float vbuf[256];
  __shared__ float comb[512];
  __shared__ float r1[256], r2[256];
  __shared__ float smu, srs;
  lxs[j] = lp[b * 256 + j];
  comb[j] = pp[b * 256 + j];
  __syncthreads();
  float v = bv[j];
  for (int k = 0; k < 256; ++k) v = fmaf(lxs[k], Wv[k * 256 + j], v);
  vbuf[j] = v;
  __syncthreads();
  float at = bo[j];
  for (int k = 0; k < 256; ++k) at = fmaf(vbuf[k], Wo[k * 256 + j], at);
  comb[256 + j] = at;
  __syncthreads();
  float h = fc1b[j];
  for (int k = 0; k < 512; ++k) h = fmaf(comb[k], fc1w[k * 256 + j], h);
  r1[j] = h;
  r2[j] = h * h;
  __syncthreads();
  for (int off = 128; off > 0; off >>= 1) {
    if (j < off) { r1[j] += r1[j + off]; r2[j] += r2[j + off]; }
    __syncthreads();
  }
  if (j == 0) {
    float mu = r1[0] / 256.f;
    float var = r2[0] / 256.f - mu * mu;
    smu = mu;
    srs = 1.f / sqrtf(var + 1e-5f);
  }
  __syncthreads();
  float hn = (h - smu) * srs * lng[j] + lnb[j];
  hn = hn > 0.f ? hn : 0.01f * hn;
  r1[j] = hn * fc2w[j];
  __syncthreads();
  for (int off = 128; off > 0; off >>= 1) {
    if (j < off) r1[j] += r1[j + off];
    __syncthreads();
  }
  if (j == 0) out[b] = r1[0] + fc2b[0];
}

static void run_side(const float* x, int K, const int* ei, int E, int N,
                     const float* W1l, const float* W1r, const float* att1, const float* b1,
                     const float* W2l, const float* W2r, const float* att2, const float* b2,
                     const int* batch, float* pool,
                     float* A, float* XL, float* XR, float* LOG, float* Mb, float* Sb,
                     hipStream_t st) {
  int tot = E + N;
  int eb = (tot + 3) / 4;
  // layer 1 (H=2, C=128)
  k_lin_small<<<N, 256, 0, st>>>(x, W1l, W1r, N, K, XL, XR);
  k_init_ms<<<(N * 2 + 255) / 256, 256, 0, st>>>(Mb, Sb, N * 2);
  k_init_bias<<<N, 256, 0, st>>>(A, b1);
  k_edge_logits<2><<<eb, 256, 0, st>>>(XL, XR, ei, E, N, att1, LOG, Mb);
  k_edge_expsum<2><<<(tot * 2 + 255) / 256, 256, 0, st>>>(ei, E, N, Mb, LOG, Sb);
  k_edge_scatter<2><<<eb, 256, 0, st>>>(XL, ei, E, N, LOG, Sb, A);
  // layer 2 (H=1, C=256)
  k_mm256<<<dim3((N + 63) / 64, 4), 256, 0, st>>>(A, W2l, XL, N);
  k_mm256<<<dim3((N + 63) / 64, 4), 256, 0, st>>>(A, W2r, XR, N);
  k_init_ms<<<(N + 255) / 256, 256, 0, st>>>(Mb, Sb, N);
  k_init_bias<<<N, 256, 0, st>>>(A, b2);
  k_edge_logits<1><<<eb, 256, 0, st>>>(XL, XR, ei, E, N, att2, LOG, Mb);
  k_edge_expsum<1><<<(tot + 255) / 256, 256, 0, st>>>(ei, E, N, Mb, LOG, Sb);
  k_edge_scatter<1><<<eb, 256, 0, st>>>(XL, ei, E, N, LOG, Sb, A);
  k_pool<<<256, 256, 0, st>>>(A, batch, N, pool);
}

extern "C" void kernel_launch(void* const* d_in, const int* in_sizes, int n_in,
                              void* d_out, int out_size, void* d_ws, size_t ws_size,
                              hipStream_t stream) {
  const float* px = (const float*)d_in[0];
  const float* lx = (const float*)d_in[1];
  const int* pei = (const int*)d_in[2];
  const int* lei = (const int*)d_in[3];
  const int* pb = (const int*)d_in[4];
  const int* lb = (const int*)d_in[5];
  const float* p1_Wl = (const float*)d_in[6];
  const float* p1_Wr = (const float*)d_in[7];
  const float* p1_att = (const float*)d_in[8];
  const float* p1_b = (const float*)d_in[9];
  const float* p2_Wl = (const float*)d_in[10];
  const float* p2_Wr = (const float*)d_in[11];
  const float* p2_att = (const float*)d_in[12];
  const float* p2_b = (const float*)d_in[13];
  const float* l1_Wl = (const float*)d_in[14];
  const float* l1_Wr = (const float*)d_in[15];
  const float* l1_att = (const float*)d_in[16];
  const float* l1_b = (const float*)d_in[17];
  const float* l2_Wl = (const float*)d_in[18];
  const float* l2_Wr = (const float*)d_in[19];
  const float* l2_att = (const float*)d_in[20];
  const float* l2_b = (const float*)d_in[21];
  const float* Wv = (const float*)d_in[26];
  const float* bv = (const float*)d_in[27];
  const float* Wo = (const float*)d_in[28];
  const float* bo = (const float*)d_in[29];
  const float* fc1w = (const float*)d_in[30];
  const float* fc1b = (const float*)d_in[31];
  const float* lng = (const float*)d_in[32];
  const float* lnb = (const float*)d_in[33];
  const float* fc2w = (const float*)d_in[34];
  const float* fc2b = (const float*)d_in[35];

  const int NPn = in_sizes[4];          // 50000
  const int NLn = in_sizes[5];          // 50000
  const int EPe = in_sizes[2] / 2;      // 400000
  const int ELe = in_sizes[3] / 2;      // 400000
  const int KP = in_sizes[0] / NPn;     // 10
  const int KL = in_sizes[1] / NLn;     // 5

  const int Nmax = NPn > NLn ? NPn : NLn;
  const int totmax = ((EPe + NPn) > (ELe + NLn)) ? (EPe + NPn) : (ELe + NLn);
  size_t NF = (size_t)Nmax * 256;

  float* A = (float*)d_ws;
  float* XL = A + NF;
  float* XR = XL + NF;
  float* LOG = XR + NF;
  float* Mb = LOG + (size_t)totmax * 2;
  float* Sb = Mb + (size_t)Nmax * 2;
  float* PP = Sb + (size_t)Nmax * 2;
  float* LP = PP + 256 * 256;

  run_side(px, KP, pei, EPe, NPn, p1_Wl, p1_Wr, p1_att, p1_b, p2_Wl, p2_Wr, p2_att, p2_b,
           pb, PP, A, XL, XR, LOG, Mb, Sb, stream);
  run_side(lx, KL, lei, ELe, NLn, l1_Wl, l1_Wr, l1_att, l1_b, l2_Wl, l2_Wr, l2_att, l2_b,
           lb, LP, A, XL, XR, LOG, Mb, Sb, stream);

  k_head<<<256, 256, 0, stream>>>(PP, LP, Wv, bv, Wo, bo, fc1w, fc1b, lng, lnb, fc2w, fc2b,
                                  (float*)d_out);
}

// Round 2
// 1166.137 us; speedup vs baseline: 6.3259x; 6.3259x over previous
//
#include <hip/hip_runtime.h>
#include <math.h>

#define LR_GAT(x) ((x) > 0.f ? (x) : 0.2f * (x))

// ---------------- layer-1 transform: xl = x@Wl, xr = x@Wr ; K <= 16, out 256 ----------------
__global__ void k_lin_small(const float* __restrict__ x, const float* __restrict__ Wl,
                            const float* __restrict__ Wr, int N, int K,
                            float* __restrict__ xl, float* __restrict__ xr) {
  int n = blockIdx.x;
  int j = threadIdx.x;
  __shared__ float xs[16];
  if (j < K) xs[j] = x[(size_t)n * K + j];
  __syncthreads();
  float al = 0.f, ar = 0.f;
  for (int k = 0; k < K; ++k) {
    float xv = xs[k];
    al = fmaf(xv, Wl[k * 256 + j], al);
    ar = fmaf(xv, Wr[k * 256 + j], ar);
  }
  xl[(size_t)n * 256 + j] = al;
  xr[(size_t)n * 256 + j] = ar;
}

// ---------------- C[N,256] = A[N,256] @ W[256,256]; 64x64 tile, 4x4 microtile, fp32 ----------------
__global__ void k_mm256(const float* __restrict__ A, const float* __restrict__ W,
                        float* __restrict__ C, int N) {
  __shared__ float As[16][64];  // [k][m]
  __shared__ float Bs[16][64];  // [k][n]
  const int m0 = blockIdx.x * 64;
  const int n0 = blockIdx.y * 64;
  const int t = threadIdx.x;
  const int tn = (t & 15) * 4;
  const int tm = (t >> 4) * 4;
  const int la_row = t >> 2;
  const int la_kq = (t & 3) * 4;
  const int lb_k = t >> 4;
  const int lb_n = (t & 15) * 4;
  const int rowA = m0 + la_row;
  float acc[4][4] = {};
  for (int kt = 0; kt < 256; kt += 16) {
    float4 a4 = make_float4(0.f, 0.f, 0.f, 0.f);
    if (rowA < N) a4 = *(const float4*)&A[(size_t)rowA * 256 + kt + la_kq];
    float4 b4 = *(const float4*)&W[(size_t)(kt + lb_k) * 256 + n0 + lb_n];
    __syncthreads();
    As[la_kq + 0][la_row] = a4.x;
    As[la_kq + 1][la_row] = a4.y;
    As[la_kq + 2][la_row] = a4.z;
    As[la_kq + 3][la_row] = a4.w;
    *(float4*)&Bs[lb_k][lb_n] = b4;
    __syncthreads();
#pragma unroll
    for (int k = 0; k < 16; ++k) {
      float4 av = *(const float4*)&As[k][tm];
      float4 bv = *(const float4*)&Bs[k][tn];
      acc[0][0] = fmaf(av.x, bv.x, acc[0][0]);
      acc[0][1] = fmaf(av.x, bv.y, acc[0][1]);
      acc[0][2] = fmaf(av.x, bv.z, acc[0][2]);
      acc[0][3] = fmaf(av.x, bv.w, acc[0][3]);
      acc[1][0] = fmaf(av.y, bv.x, acc[1][0]);
      acc[1][1] = fmaf(av.y, bv.y, acc[1][1]);
      acc[1][2] = fmaf(av.y, bv.z, acc[1][2]);
      acc[1][3] = fmaf(av.y, bv.w, acc[1][3]);
      acc[2][0] = fmaf(av.z, bv.x, acc[2][0]);
      acc[2][1] = fmaf(av.z, bv.y, acc[2][1]);
      acc[2][2] = fmaf(av.z, bv.z, acc[2][2]);
      acc[2][3] = fmaf(av.z, bv.w, acc[2][3]);
      acc[3][0] = fmaf(av.w, bv.x, acc[3][0]);
      acc[3][1] = fmaf(av.w, bv.y, acc[3][1]);
      acc[3][2] = fmaf(av.w, bv.z, acc[3][2]);
      acc[3][3] = fmaf(av.w, bv.w, acc[3][3]);
    }
  }
#pragma unroll
  for (int r = 0; r < 4; ++r) {
    int row = m0 + tm + r;
    if (row < N)
      *(float4*)&C[(size_t)row * 256 + n0 + tn] =
          make_float4(acc[r][0], acc[r][1], acc[r][2], acc[r][3]);
  }
}

// ---------------- CSR build (dst-sorted) ----------------
__global__ void k_zero2(int* __restrict__ a, int* __restrict__ b, int n) {
  int i = blockIdx.x * blockDim.x + threadIdx.x;
  if (i < n) { a[i] = 0; b[i] = 0; }
}

__global__ void k_hist(const int* __restrict__ ei, int E, int* __restrict__ cnt) {
  int e = blockIdx.x * blockDim.x + threadIdx.x;
  if (e < E) atomicAdd(&cnt[ei[E + e]], 1);
}

// per-block exclusive scan (256/block) + block sums
__global__ void k_scan1(const int* __restrict__ cnt, int N, int* __restrict__ offs,
                        int* __restrict__ bsum) {
  __shared__ int s[256];
  int tid = threadIdx.x;
  int i = blockIdx.x * 256 + tid;
  int v = (i < N) ? cnt[i] : 0;
  s[tid] = v;
  __syncthreads();
  for (int off = 1; off < 256; off <<= 1) {
    int t = 0;
    if (tid >= off) t = s[tid - off];
    __syncthreads();
    if (tid >= off) s[tid] += t;
    __syncthreads();
  }
  if (i < N) offs[i] = s[tid] - v;
  if (tid == 255) bsum[blockIdx.x] = s[255];
}

// single-block exclusive scan of block sums (nb <= 256)
__global__ void k_scan2(int* __restrict__ bsum, int nb) {
  __shared__ int s[256];
  int tid = threadIdx.x;
  int v = (tid < nb) ? bsum[tid] : 0;
  s[tid] = v;
  __syncthreads();
  for (int off = 1; off < 256; off <<= 1) {
    int t = 0;
    if (tid >= off) t = s[tid - off];
    __syncthreads();
    if (tid >= off) s[tid] += t;
    __syncthreads();
  }
  if (tid < nb) bsum[tid] = s[tid] - v;
}

__global__ void k_scan3(int* __restrict__ offs, const int* __restrict__ bsum, int N) {
  int i = blockIdx.x * 256 + threadIdx.x;
  if (i < N) offs[i] += bsum[blockIdx.x];
}

__global__ void k_fill(const int* __restrict__ ei, int E, const int* __restrict__ offs,
                       int* __restrict__ cur, int* __restrict__ csr_src) {
  int e = blockIdx.x * blockDim.x + threadIdx.x;
  if (e >= E) return;
  int d = ei[E + e];
  int pos = offs[d] + atomicAdd(&cur[d], 1);
  csr_src[pos] = ei[e];
}

// ---------------- fused GATv2 aggregation: one wave per destination, online softmax ----------------
// channel layout: lane*4 .. lane*4+3 ; H==2 -> head = lane>>5 (att flat [H*C]=256 matches)
template <int H>
__global__ void k_gat_gather(const float* __restrict__ xl, const float* __restrict__ xr,
                             const int* __restrict__ csr_src, const int* __restrict__ offs,
                             const int* __restrict__ cnt, const float* __restrict__ att,
                             const float* __restrict__ bias, int N,
                             float* __restrict__ out) {
  int d = blockIdx.x * 4 + (threadIdx.x >> 6);
  if (d >= N) return;
  int lane = threadIdx.x & 63;
  const float4 rd = *(const float4*)&xr[(size_t)d * 256 + lane * 4];
  const float4 wa = *(const float4*)&att[lane * 4];
  const float4 xd = *(const float4*)&xl[(size_t)d * 256 + lane * 4];
  // self-loop (always present)
  float p = LR_GAT(xd.x + rd.x) * wa.x + LR_GAT(xd.y + rd.y) * wa.y +
            LR_GAT(xd.z + rd.z) * wa.z + LR_GAT(xd.w + rd.w) * wa.w;
#pragma unroll
  for (int off = 1; off <= (H == 2 ? 16 : 32); off <<= 1) p += __shfl_xor(p, off, 64);
  float m = p, l = 1.f;
  float4 acc = xd;
  const int o0 = offs[d];
  const int c = cnt[d];
  for (int j = 0; j < c; ++j) {
    int s = csr_src[o0 + j];
    float4 a = *(const float4*)&xl[(size_t)s * 256 + lane * 4];
    float q = LR_GAT(a.x + rd.x) * wa.x + LR_GAT(a.y + rd.y) * wa.y +
              LR_GAT(a.z + rd.z) * wa.z + LR_GAT(a.w + rd.w) * wa.w;
#pragma unroll
    for (int off = 1; off <= (H == 2 ? 16 : 32); off <<= 1) q += __shfl_xor(q, off, 64);
    float mn = fmaxf(m, q);
    float sc = expf(m - mn);
    float w = expf(q - mn);
    l = l * sc + w;
    acc.x = acc.x * sc + w * a.x;
    acc.y = acc.y * sc + w * a.y;
    acc.z = acc.z * sc + w * a.z;
    acc.w = acc.w * sc + w * a.w;
    m = mn;
  }
  float inv = 1.f / l;
  const float4 b4 = *(const float4*)&bias[lane * 4];
  float4 o;
  o.x = acc.x * inv + b4.x;
  o.y = acc.y * inv + b4.y;
  o.z = acc.z * inv + b4.z;
  o.w = acc.w * inv + b4.w;
  *(float4*)&out[(size_t)d * 256 + lane * 4] = o;
}

// ---------------- mean pool over sorted batch ids ----------------
__global__ void k_pool(const float* __restrict__ x, const int* __restrict__ batch, int N,
                       float* __restrict__ pool) {
  int b = blockIdx.x;
  int j = threadIdx.x;
  __shared__ int sss, sse;
  if (j == 0) {
    int lo = 0, hi = N;
    while (lo < hi) { int mid = (lo + hi) >> 1; if (batch[mid] < b) lo = mid + 1; else hi = mid; }
    sss = lo;
    lo = 0; hi = N;
    while (lo < hi) { int mid = (lo + hi) >> 1; if (batch[mid] < b + 1) lo = mid + 1; else hi = mid; }
    sse = lo;
  }
  __syncthreads();
  float acc = 0.f;
  for (int n = sss; n < sse; ++n) acc += x[(size_t)n * 256 + j];
  float cnt = (float)(sse - sss);
  pool[b * 256 + j] = acc / fmaxf(cnt, 1.f);
}

// ---------------- fused head ----------------
__global__ void k_head(const float* __restrict__ pp, const float* __restrict__ lp,
                       const float* __restrict__ Wv, const float* __restrict__ bv,
                       const float* __restrict__ Wo, const float* __restrict__ bo,
                       const float* __restrict__ fc1w, const float* __restrict__ fc1b,
                       const float* __restrict__ lng, const float* __restrict__ lnb,
                       const float* __restrict__ fc2w, const float* __restrict__ fc2b,
                       float* __restrict__ out) {
  int b = blockIdx.x;
  int j = threadIdx.x;
  __shared__ float lxs[256];
  __shared__ float vbuf[256];
  __shared__ float comb[512];
  __shared__ float r1[256], r2[256];
  __shared__ float smu, srs;
  lxs[j] = lp[b * 256 + j];
  comb[j] = pp[b * 256 + j];
  __syncthreads();
  float v = bv[j];
  for (int k = 0; k < 256; ++k) v = fmaf(lxs[k], Wv[k * 256 + j], v);
  vbuf[j] = v;
  __syncthreads();
  float at = bo[j];
  for (int k = 0; k < 256; ++k) at = fmaf(vbuf[k], Wo[k * 256 + j], at);
  comb[256 + j] = at;
  __syncthreads();
  float h = fc1b[j];
  for (int k = 0; k < 512; ++k) h = fmaf(comb[k], fc1w[k * 256 + j], h);
  r1[j] = h;
  r2[j] = h * h;
  __syncthreads();
  for (int off = 128; off > 0; off >>= 1) {
    if (j < off) { r1[j] += r1[j + off]; r2[j] += r2[j + off]; }
    __syncthreads();
  }
  if (j == 0) {
    float mu = r1[0] / 256.f;
    float var = r2[0] / 256.f - mu * mu;
    smu = mu;
    srs = 1.f / sqrtf(var + 1e-5f);
  }
  __syncthreads();
  float hn = (h - smu) * srs * lng[j] + lnb[j];
  hn = hn > 0.f ? hn : 0.01f * hn;
  r1[j] = hn * fc2w[j];
  __syncthreads();
  for (int off = 128; off > 0; off >>= 1) {
    if (j < off) r1[j] += r1[j + off];
    __syncthreads();
  }
  if (j == 0) out[b] = r1[0] + fc2b[0];
}

// ---------------- per-side driver ----------------
static void run_side(const float* x, int K, const int* ei, int E, int N,
                     const float* W1l, const float* W1r, const float* att1, const float* b1,
                     const float* W2l, const float* W2r, const float* att2, const float* b2,
                     const int* batch, float* pool,
                     float* A, float* XL, float* XR,
                     int* cnt, int* cur, int* offs, int* bsum, int* csr_src,
                     hipStream_t st) {
  const int nb = (N + 255) / 256;
  // CSR build (shared by both layers of this side)
  k_zero2<<<nb, 256, 0, st>>>(cnt, cur, N);
  k_hist<<<(E + 255) / 256, 256, 0, st>>>(ei, E, cnt);
  k_scan1<<<nb, 256, 0, st>>>(cnt, N, offs, bsum);
  k_scan2<<<1, 256, 0, st>>>(bsum, nb);
  k_scan3<<<nb, 256, 0, st>>>(offs, bsum, N);
  k_fill<<<(E + 255) / 256, 256, 0, st>>>(ei, E, offs, cur, csr_src);

  const int gb = (N + 3) / 4;
  // layer 1 (H=2, C=128)
  k_lin_small<<<N, 256, 0, st>>>(x, W1l, W1r, N, K, XL, XR);
  k_gat_gather<2><<<gb, 256, 0, st>>>(XL, XR, csr_src, offs, cnt, att1, b1, N, A);
  // layer 2 (H=1, C=256)
  k_mm256<<<dim3((N + 63) / 64, 4), 256, 0, st>>>(A, W2l, XL, N);
  k_mm256<<<dim3((N + 63) / 64, 4), 256, 0, st>>>(A, W2r, XR, N);
  k_gat_gather<1><<<gb, 256, 0, st>>>(XL, XR, csr_src, offs, cnt, att2, b2, N, A);
  k_pool<<<256, 256, 0, st>>>(A, batch, N, pool);
}

extern "C" void kernel_launch(void* const* d_in, const int* in_sizes, int n_in,
                              void* d_out, int out_size, void* d_ws, size_t ws_size,
                              hipStream_t stream) {
  const float* px = (const float*)d_in[0];
  const float* lx = (const float*)d_in[1];
  const int* pei = (const int*)d_in[2];
  const int* lei = (const int*)d_in[3];
  const int* pb = (const int*)d_in[4];
  const int* lb = (const int*)d_in[5];
  const float* p1_Wl = (const float*)d_in[6];
  const float* p1_Wr = (const float*)d_in[7];
  const float* p1_att = (const float*)d_in[8];
  const float* p1_b = (const float*)d_in[9];
  const float* p2_Wl = (const float*)d_in[10];
  const float* p2_Wr = (const float*)d_in[11];
  const float* p2_att = (const float*)d_in[12];
  const float* p2_b = (const float*)d_in[13];
  const float* l1_Wl = (const float*)d_in[14];
  const float* l1_Wr = (const float*)d_in[15];
  const float* l1_att = (const float*)d_in[16];
  const float* l1_b = (const float*)d_in[17];
  const float* l2_Wl = (const float*)d_in[18];
  const float* l2_Wr = (const float*)d_in[19];
  const float* l2_att = (const float*)d_in[20];
  const float* l2_b = (const float*)d_in[21];
  const float* Wv = (const float*)d_in[26];
  const float* bv = (const float*)d_in[27];
  const float* Wo = (const float*)d_in[28];
  const float* bo = (const float*)d_in[29];
  const float* fc1w = (const float*)d_in[30];
  const float* fc1b = (const float*)d_in[31];
  const float* lng = (const float*)d_in[32];
  const float* lnb = (const float*)d_in[33];
  const float* fc2w = (const float*)d_in[34];
  const float* fc2b = (const float*)d_in[35];

  const int NPn = in_sizes[4];
  const int NLn = in_sizes[5];
  const int EPe = in_sizes[2] / 2;
  const int ELe = in_sizes[3] / 2;
  const int KP = in_sizes[0] / NPn;
  const int KL = in_sizes[1] / NLn;

  const int Nmax = NPn > NLn ? NPn : NLn;
  const int Emax = EPe > ELe ? EPe : ELe;
  size_t NF = (size_t)Nmax * 256;

  float* A = (float*)d_ws;
  float* XL = A + NF;
  float* XR = XL + NF;
  float* PP = XR + NF;
  float* LP = PP + 256 * 256;
  int* cnt = (int*)(LP + 256 * 256);
  int* cur = cnt + Nmax;
  int* offs = cur + Nmax;
  int* bsum = offs + Nmax;
  int* csr_src = bsum + 256;

  run_side(px, KP, pei, EPe, NPn, p1_Wl, p1_Wr, p1_att, p1_b, p2_Wl, p2_Wr, p2_att, p2_b,
           pb, PP, A, XL, XR, cnt, cur, offs, bsum, csr_src, stream);
  run_side(lx, KL, lei, ELe, NLn, l1_Wl, l1_Wr, l1_att, l1_b, l2_Wl, l2_Wr, l2_att, l2_b,
           lb, LP, A, XL, XR, cnt, cur, offs, bsum, csr_src, stream);

  k_head<<<256, 256, 0, stream>>>(PP, LP, Wv, bv, Wo, bo, fc1w, fc1b, lng, lnb, fc2w, fc2b,
                                  (float*)d_out);
  (void)Emax; (void)n_in; (void)out_size; (void)ws_size;
}

// Round 3
// 926.353 us; speedup vs baseline: 7.9634x; 1.2588x over previous
//
#include <hip/hip_runtime.h>
#include <math.h>

#define LR_GAT(x) ((x) > 0.f ? (x) : 0.2f * (x))

typedef unsigned short u16;
typedef __attribute__((ext_vector_type(8))) short bf16x8;
typedef __attribute__((ext_vector_type(4))) float f32x4;

__device__ inline u16 f2bf(float x) {
  unsigned int u = __float_as_uint(x);
  u += 0x7fffu + ((u >> 16) & 1u);
  return (u16)(u >> 16);
}
__device__ inline float bf2f(u16 h) {
  return __uint_as_float(((unsigned int)h) << 16);
}

// ---------------- layer-1 transform: xl = x@Wl, xr = x@Wr ; K <= 16, out 256 ----------------
__global__ void k_lin_small(const float* __restrict__ x, const float* __restrict__ Wl,
                            const float* __restrict__ Wr, int N, int K,
                            float* __restrict__ xl, float* __restrict__ xr) {
  int n = blockIdx.x;
  int j = threadIdx.x;
  __shared__ float xs[16];
  if (j < K) xs[j] = x[(size_t)n * K + j];
  __syncthreads();
  float al = 0.f, ar = 0.f;
  for (int k = 0; k < K; ++k) {
    float xv = xs[k];
    al = fmaf(xv, Wl[k * 256 + j], al);
    ar = fmaf(xv, Wr[k * 256 + j], ar);
  }
  xl[(size_t)n * 256 + j] = al;
  xr[(size_t)n * 256 + j] = ar;
}

// ---------------- weight split+transpose: Wt[n][k] (n: 0-255 Wl cols, 256-511 Wr cols) ----------------
__global__ void k_wsplit(const float* __restrict__ Wl, const float* __restrict__ Wr,
                         u16* __restrict__ Wh, u16* __restrict__ Wlo) {
  int n = blockIdx.x;   // 0..511
  int k = threadIdx.x;  // 0..255
  float w = (n < 256) ? Wl[k * 256 + n] : Wr[k * 256 + (n - 256)];
  u16 hb = f2bf(w);
  Wh[n * 256 + k] = hb;
  Wlo[n * 256 + k] = f2bf(w - bf2f(hb));
}

// ---------------- dual GEMM via split-bf16 MFMA ----------------
// XL[M,256] = A@Wl, XR[M,256] = A@Wr ; A given as hi/lo bf16 [M,256]; Wt [512,256] (pre-T).
// 128x128 tile, BK=32, 4 waves, each wave 4x4 frags of 16x16x32. XOR-swizzled LDS.
__global__ void __launch_bounds__(256, 2) k_mm_dual(
    const u16* __restrict__ Ahi, const u16* __restrict__ Alo,
    const u16* __restrict__ Bhi, const u16* __restrict__ Blo,
    float* __restrict__ XL, float* __restrict__ XR, int M) {
  __shared__ __align__(16) char smem[32768];
  char* sAh = smem;
  char* sAl = smem + 8192;
  char* sBh = smem + 16384;
  char* sBl = smem + 24576;
  const int t = threadIdx.x;
  const int rowBase = blockIdx.x * 128;
  const int j0 = blockIdx.y * 128;
  const int srow = t >> 1;  // 0..127
  const int h = t & 1;      // 32-B half of the 64-B row
  int gr = rowBase + srow;
  if (gr >= M) gr = M - 1;
  const size_t gaBase = (size_t)gr * 256 + h * 16;
  const size_t gbBase = (size_t)(j0 + srow) * 256 + h * 16;
  const int rb = srow * 64;
  const int sw0 = (((h * 2) + (srow >> 1)) & 3) * 16;
  const int sw1 = (((h * 2 + 1) + (srow >> 1)) & 3) * 16;
  const int lane = t & 63;
  const int wid = t >> 6;
  const int wm = (wid & 1) * 64;
  const int wn = (wid >> 1) * 64;
  const int kq = lane >> 4;
  const int mr = lane & 15;
  int offA[4], offB[4];
#pragma unroll
  for (int i = 0; i < 4; ++i) {
    int m = wm + i * 16 + mr;
    offA[i] = m * 64 + ((kq + (m >> 1)) & 3) * 16;
    int n = wn + i * 16 + mr;
    offB[i] = n * 64 + ((kq + (n >> 1)) & 3) * 16;
  }
  f32x4 acc[4][4] = {};
  for (int kt = 0; kt < 8; ++kt) {
    const int k0 = kt * 32;
    uint4 vah0 = *(const uint4*)(Ahi + gaBase + k0);
    uint4 vah1 = *(const uint4*)(Ahi + gaBase + k0 + 8);
    uint4 val0 = *(const uint4*)(Alo + gaBase + k0);
    uint4 val1 = *(const uint4*)(Alo + gaBase + k0 + 8);
    uint4 vbh0 = *(const uint4*)(Bhi + gbBase + k0);
    uint4 vbh1 = *(const uint4*)(Bhi + gbBase + k0 + 8);
    uint4 vbl0 = *(const uint4*)(Blo + gbBase + k0);
    uint4 vbl1 = *(const uint4*)(Blo + gbBase + k0 + 8);
    __syncthreads();
    *(uint4*)(sAh + rb + sw0) = vah0;
    *(uint4*)(sAh + rb + sw1) = vah1;
    *(uint4*)(sAl + rb + sw0) = val0;
    *(uint4*)(sAl + rb + sw1) = val1;
    *(uint4*)(sBh + rb + sw0) = vbh0;
    *(uint4*)(sBh + rb + sw1) = vbh1;
    *(uint4*)(sBl + rb + sw0) = vbl0;
    *(uint4*)(sBl + rb + sw1) = vbl1;
    __syncthreads();
    bf16x8 ah[4], al4[4], bh[4], bl4[4];
#pragma unroll
    for (int i = 0; i < 4; ++i) {
      ah[i] = *(const bf16x8*)(sAh + offA[i]);
      al4[i] = *(const bf16x8*)(sAl + offA[i]);
      bh[i] = *(const bf16x8*)(sBh + offB[i]);
      bl4[i] = *(const bf16x8*)(sBl + offB[i]);
    }
#pragma unroll
    for (int i = 0; i < 4; ++i)
#pragma unroll
      for (int j = 0; j < 4; ++j) {
        acc[i][j] = __builtin_amdgcn_mfma_f32_16x16x32_bf16(ah[i], bh[j], acc[i][j], 0, 0, 0);
        acc[i][j] = __builtin_amdgcn_mfma_f32_16x16x32_bf16(ah[i], bl4[j], acc[i][j], 0, 0, 0);
        acc[i][j] = __builtin_amdgcn_mfma_f32_16x16x32_bf16(al4[i], bh[j], acc[i][j], 0, 0, 0);
      }
  }
  float* cbase;
  int cb;
  if (blockIdx.y < 2) { cbase = XL; cb = j0; } else { cbase = XR; cb = j0 - 256; }
#pragma unroll
  for (int i = 0; i < 4; ++i) {
    int row0 = rowBase + wm + i * 16 + (lane >> 4) * 4;
#pragma unroll
    for (int j = 0; j < 4; ++j) {
      int col = cb + wn + j * 16 + mr;
#pragma unroll
      for (int r = 0; r < 4; ++r) {
        int row = row0 + r;
        if (row < M) cbase[(size_t)row * 256 + col] = acc[i][j][r];
      }
    }
  }
}

// ---------------- CSR build (dst-sorted) ----------------
__global__ void k_zero2(int* __restrict__ a, int* __restrict__ b, int n) {
  int i = blockIdx.x * blockDim.x + threadIdx.x;
  if (i < n) { a[i] = 0; b[i] = 0; }
}

__global__ void k_hist(const int* __restrict__ ei, int E, int* __restrict__ cnt) {
  int e = blockIdx.x * blockDim.x + threadIdx.x;
  if (e < E) atomicAdd(&cnt[ei[E + e]], 1);
}

__global__ void k_scan1(const int* __restrict__ cnt, int N, int* __restrict__ offs,
                        int* __restrict__ bsum) {
  __shared__ int s[256];
  int tid = threadIdx.x;
  int i = blockIdx.x * 256 + tid;
  int v = (i < N) ? cnt[i] : 0;
  s[tid] = v;
  __syncthreads();
  for (int off = 1; off < 256; off <<= 1) {
    int t = 0;
    if (tid >= off) t = s[tid - off];
    __syncthreads();
    if (tid >= off) s[tid] += t;
    __syncthreads();
  }
  if (i < N) offs[i] = s[tid] - v;
  if (tid == 255) bsum[blockIdx.x] = s[255];
}

__global__ void k_scan2(int* __restrict__ bsum, int nb) {
  __shared__ int s[256];
  int tid = threadIdx.x;
  int v = (tid < nb) ? bsum[tid] : 0;
  s[tid] = v;
  __syncthreads();
  for (int off = 1; off < 256; off <<= 1) {
    int t = 0;
    if (tid >= off) t = s[tid - off];
    __syncthreads();
    if (tid >= off) s[tid] += t;
    __syncthreads();
  }
  if (tid < nb) bsum[tid] = s[tid] - v;
}

__global__ void k_scan3(int* __restrict__ offs, const int* __restrict__ bsum, int N) {
  int i = blockIdx.x * 256 + threadIdx.x;
  if (i < N) offs[i] += bsum[blockIdx.x];
}

__global__ void k_fill(const int* __restrict__ ei, int E, const int* __restrict__ offs,
                       int* __restrict__ cur, int* __restrict__ csr_src) {
  int e = blockIdx.x * blockDim.x + threadIdx.x;
  if (e >= E) return;
  int d = ei[E + e];
  int pos = offs[d] + atomicAdd(&cur[d], 1);
  csr_src[pos] = ei[e];
}

// ---------------- fused GATv2 aggregation: one wave per destination, online softmax ----------------
// SPLIT: write hi/lo bf16 (feeds MFMA GEMM); else write fp32.
template <int H, bool SPLIT>
__global__ void k_gat_gather(const float* __restrict__ xl, const float* __restrict__ xr,
                             const int* __restrict__ csr_src, const int* __restrict__ offs,
                             const int* __restrict__ cnt, const float* __restrict__ att,
                             const float* __restrict__ bias, int N,
                             float* __restrict__ outf, u16* __restrict__ ohi,
                             u16* __restrict__ olo) {
  int d = blockIdx.x * 4 + (threadIdx.x >> 6);
  if (d >= N) return;
  int lane = threadIdx.x & 63;
  const float4 rd = *(const float4*)&xr[(size_t)d * 256 + lane * 4];
  const float4 wa = *(const float4*)&att[lane * 4];
  const float4 xd = *(const float4*)&xl[(size_t)d * 256 + lane * 4];
  float p = LR_GAT(xd.x + rd.x) * wa.x + LR_GAT(xd.y + rd.y) * wa.y +
            LR_GAT(xd.z + rd.z) * wa.z + LR_GAT(xd.w + rd.w) * wa.w;
#pragma unroll
  for (int off = 1; off <= (H == 2 ? 16 : 32); off <<= 1) p += __shfl_xor(p, off, 64);
  float m = p, l = 1.f;
  float4 acc = xd;
  const int o0 = offs[d];
  const int c = cnt[d];
  for (int j = 0; j < c; ++j) {
    int s = csr_src[o0 + j];
    float4 a = *(const float4*)&xl[(size_t)s * 256 + lane * 4];
    float q = LR_GAT(a.x + rd.x) * wa.x + LR_GAT(a.y + rd.y) * wa.y +
              LR_GAT(a.z + rd.z) * wa.z + LR_GAT(a.w + rd.w) * wa.w;
#pragma unroll
    for (int off = 1; off <= (H == 2 ? 16 : 32); off <<= 1) q += __shfl_xor(q, off, 64);
    float mn = fmaxf(m, q);
    float sc = expf(m - mn);
    float w = expf(q - mn);
    l = l * sc + w;
    acc.x = acc.x * sc + w * a.x;
    acc.y = acc.y * sc + w * a.y;
    acc.z = acc.z * sc + w * a.z;
    acc.w = acc.w * sc + w * a.w;
    m = mn;
  }
  float inv = 1.f / l;
  const float4 b4 = *(const float4*)&bias[lane * 4];
  float4 o;
  o.x = acc.x * inv + b4.x;
  o.y = acc.y * inv + b4.y;
  o.z = acc.z * inv + b4.z;
  o.w = acc.w * inv + b4.w;
  if (SPLIT) {
    ushort4 hv, lv;
    hv.x = f2bf(o.x); lv.x = f2bf(o.x - bf2f(hv.x));
    hv.y = f2bf(o.y); lv.y = f2bf(o.y - bf2f(hv.y));
    hv.z = f2bf(o.z); lv.z = f2bf(o.z - bf2f(hv.z));
    hv.w = f2bf(o.w); lv.w = f2bf(o.w - bf2f(hv.w));
    *(ushort4*)&ohi[(size_t)d * 256 + lane * 4] = hv;
    *(ushort4*)&olo[(size_t)d * 256 + lane * 4] = lv;
  } else {
    *(float4*)&outf[(size_t)d * 256 + lane * 4] = o;
  }
}

// ---------------- mean pool over sorted batch ids ----------------
__global__ void k_pool(const float* __restrict__ x, const int* __restrict__ batch, int N,
                       float* __restrict__ pool) {
  int b = blockIdx.x;
  int j = threadIdx.x;
  __shared__ int sss, sse;
  if (j == 0) {
    int lo = 0, hi = N;
    while (lo < hi) { int mid = (lo + hi) >> 1; if (batch[mid] < b) lo = mid + 1; else hi = mid; }
    sss = lo;
    lo = 0; hi = N;
    while (lo < hi) { int mid = (lo + hi) >> 1; if (batch[mid] < b + 1) lo = mid + 1; else hi = mid; }
    sse = lo;
  }
  __syncthreads();
  float acc = 0.f;
  for (int n = sss; n < sse; ++n) acc += x[(size_t)n * 256 + j];
  float cntf = (float)(sse - sss);
  pool[b * 256 + j] = acc / fmaxf(cntf, 1.f);
}

// ---------------- fused head ----------------
__global__ void k_head(const float* __restrict__ pp, const float* __restrict__ lp,
                       const float* __restrict__ Wv, const float* __restrict__ bv,
                       const float* __restrict__ Wo, const float* __restrict__ bo,
                       const float* __restrict__ fc1w, const float* __restrict__ fc1b,
                       const float* __restrict__ lng, const float* __restrict__ lnb,
                       const float* __restrict__ fc2w, const float* __restrict__ fc2b,
                       float* __restrict__ out) {
  int b = blockIdx.x;
  int j = threadIdx.x;
  __shared__ float lxs[256];
  __shared__ float vbuf[256];
  __shared__ float comb[512];
  __shared__ float r1[256], r2[256];
  __shared__ float smu, srs;
  lxs[j] = lp[b * 256 + j];
  comb[j] = pp[b * 256 + j];
  __syncthreads();
  float v = bv[j];
  for (int k = 0; k < 256; ++k) v = fmaf(lxs[k], Wv[k * 256 + j], v);
  vbuf[j] = v;
  __syncthreads();
  float at = bo[j];
  for (int k = 0; k < 256; ++k) at = fmaf(vbuf[k], Wo[k * 256 + j], at);
  comb[256 + j] = at;
  __syncthreads();
  float h = fc1b[j];
  for (int k = 0; k < 512; ++k) h = fmaf(comb[k], fc1w[k * 256 + j], h);
  r1[j] = h;
  r2[j] = h * h;
  __syncthreads();
  for (int off = 128; off > 0; off >>= 1) {
    if (j < off) { r1[j] += r1[j + off]; r2[j] += r2[j + off]; }
    __syncthreads();
  }
  if (j == 0) {
    float mu = r1[0] / 256.f;
    float var = r2[0] / 256.f - mu * mu;
    smu = mu;
    srs = 1.f / sqrtf(var + 1e-5f);
  }
  __syncthreads();
  float hn = (h - smu) * srs * lng[j] + lnb[j];
  hn = hn > 0.f ? hn : 0.01f * hn;
  r1[j] = hn * fc2w[j];
  __syncthreads();
  for (int off = 128; off > 0; off >>= 1) {
    if (j < off) r1[j] += r1[j + off];
    __syncthreads();
  }
  if (j == 0) out[b] = r1[0] + fc2b[0];
}

// ---------------- per-side driver ----------------
static void run_side(const float* x, int K, const int* ei, int E, int N,
                     const float* W1l, const float* W1r, const float* att1, const float* b1,
                     const float* W2l, const float* W2r, const float* att2, const float* b2,
                     const int* batch, float* pool,
                     float* XL, float* XR, float* A2, u16* Ahi, u16* Alo,
                     u16* Wth, u16* Wtl,
                     int* cnt, int* cur, int* offs, int* bsum, int* csr_src,
                     hipStream_t st) {
  const int nb = (N + 255) / 256;
  k_zero2<<<nb, 256, 0, st>>>(cnt, cur, N);
  k_hist<<<(E + 255) / 256, 256, 0, st>>>(ei, E, cnt);
  k_scan1<<<nb, 256, 0, st>>>(cnt, N, offs, bsum);
  k_scan2<<<1, 256, 0, st>>>(bsum, nb);
  k_scan3<<<nb, 256, 0, st>>>(offs, bsum, N);
  k_fill<<<(E + 255) / 256, 256, 0, st>>>(ei, E, offs, cur, csr_src);

  const int gb = (N + 3) / 4;
  // layer 1 (H=2): write split bf16 for the MFMA GEMM
  k_lin_small<<<N, 256, 0, st>>>(x, W1l, W1r, N, K, XL, XR);
  k_gat_gather<2, true><<<gb, 256, 0, st>>>(XL, XR, csr_src, offs, cnt, att1, b1, N,
                                            nullptr, Ahi, Alo);
  // layer 2 (H=1): dual split-bf16 MFMA GEMM -> XL, XR
  k_wsplit<<<512, 256, 0, st>>>(W2l, W2r, Wth, Wtl);
  k_mm_dual<<<dim3((N + 127) / 128, 4), 256, 0, st>>>(Ahi, Alo, Wth, Wtl, XL, XR, N);
  k_gat_gather<1, false><<<gb, 256, 0, st>>>(XL, XR, csr_src, offs, cnt, att2, b2, N,
                                             A2, nullptr, nullptr);
  k_pool<<<256, 256, 0, st>>>(A2, batch, N, pool);
}

extern "C" void kernel_launch(void* const* d_in, const int* in_sizes, int n_in,
                              void* d_out, int out_size, void* d_ws, size_t ws_size,
                              hipStream_t stream) {
  const float* px = (const float*)d_in[0];
  const float* lx = (const float*)d_in[1];
  const int* pei = (const int*)d_in[2];
  const int* lei = (const int*)d_in[3];
  const int* pb = (const int*)d_in[4];
  const int* lb = (const int*)d_in[5];
  const float* p1_Wl = (const float*)d_in[6];
  const float* p1_Wr = (const float*)d_in[7];
  const float* p1_att = (const float*)d_in[8];
  const float* p1_b = (const float*)d_in[9];
  const float* p2_Wl = (const float*)d_in[10];
  const float* p2_Wr = (const float*)d_in[11];
  const float* p2_att = (const float*)d_in[12];
  const float* p2_b = (const float*)d_in[13];
  const float* l1_Wl = (const float*)d_in[14];
  const float* l1_Wr = (const float*)d_in[15];
  const float* l1_att = (const float*)d_in[16];
  const float* l1_b = (const float*)d_in[17];
  const float* l2_Wl = (const float*)d_in[18];
  const float* l2_Wr = (const float*)d_in[19];
  const float* l2_att = (const float*)d_in[20];
  const float* l2_b = (const float*)d_in[21];
  const float* Wv = (const float*)d_in[26];
  const float* bv = (const float*)d_in[27];
  const float* Wo = (const float*)d_in[28];
  const float* bo = (const float*)d_in[29];
  const float* fc1w = (const float*)d_in[30];
  const float* fc1b = (const float*)d_in[31];
  const float* lng = (const float*)d_in[32];
  const float* lnb = (const float*)d_in[33];
  const float* fc2w = (const float*)d_in[34];
  const float* fc2b = (const float*)d_in[35];

  const int NPn = in_sizes[4];
  const int NLn = in_sizes[5];
  const int EPe = in_sizes[2] / 2;
  const int ELe = in_sizes[3] / 2;
  const int KP = in_sizes[0] / NPn;
  const int KL = in_sizes[1] / NLn;

  const int Nmax = NPn > NLn ? NPn : NLn;
  size_t NF = (size_t)Nmax * 256;

  float* XL = (float*)d_ws;
  float* XR = XL + NF;
  u16* Ahi = (u16*)(XR + NF);
  u16* Alo = Ahi + NF;
  float* A2 = (float*)Ahi;  // aliases Ahi/Alo, used only after k_mm_dual consumed them
  u16* Wth = Alo + NF;
  u16* Wtl = Wth + 512 * 256;
  float* PP = (float*)(Wtl + 512 * 256);
  float* LP = PP + 256 * 256;
  int* cnt = (int*)(LP + 256 * 256);
  int* cur = cnt + Nmax;
  int* offs = cur + Nmax;
  int* bsum = offs + Nmax;
  int* csr_src = bsum + 256;

  run_side(px, KP, pei, EPe, NPn, p1_Wl, p1_Wr, p1_att, p1_b, p2_Wl, p2_Wr, p2_att, p2_b,
           pb, PP, XL, XR, A2, Ahi, Alo, Wth, Wtl, cnt, cur, offs, bsum, csr_src, stream);
  run_side(lx, KL, lei, ELe, NLn, l1_Wl, l1_Wr, l1_att, l1_b, l2_Wl, l2_Wr, l2_att, l2_b,
           lb, LP, XL, XR, A2, Ahi, Alo, Wth, Wtl, cnt, cur, offs, bsum, csr_src, stream);

  k_head<<<256, 256, 0, stream>>>(PP, LP, Wv, bv, Wo, bo, fc1w, fc1b, lng, lnb, fc2w, fc2b,
                                  (float*)d_out);
  (void)n_in; (void)out_size; (void)ws_size;
}

// Round 4
// 861.218 us; speedup vs baseline: 8.5657x; 1.0756x over previous
//
#include <hip/hip_runtime.h>
#include <math.h>

#define LR_GAT(x) ((x) > 0.f ? (x) : 0.2f * (x))

typedef unsigned short u16;
typedef __attribute__((ext_vector_type(8))) short bf16x8;
typedef __attribute__((ext_vector_type(4))) float f32x4;

__device__ inline u16 f2bf(float x) {
  unsigned int u = __float_as_uint(x);
  u += 0x7fffu + ((u >> 16) & 1u);
  return (u16)(u >> 16);
}
__device__ inline float bf2f(u16 h) {
  return __uint_as_float(((unsigned int)h) << 16);
}

// ---------------- layer-1 transform: 8 nodes/block ----------------
__global__ void k_lin_small(const float* __restrict__ x, const float* __restrict__ Wl,
                            const float* __restrict__ Wr, int N, int K,
                            float* __restrict__ xl, float* __restrict__ xr) {
  int base = blockIdx.x * 8;
  int j = threadIdx.x;
  __shared__ float xs[8][16];
  int tot = 8 * K;
  for (int i = j; i < tot; i += 256) {
    int r = i / K, k = i - r * K;
    if (base + r < N) xs[r][k] = x[(size_t)(base + r) * K + k];
  }
  __syncthreads();
#pragma unroll
  for (int r = 0; r < 8; ++r) {
    int n = base + r;
    if (n >= N) break;
    float al = 0.f, ar = 0.f;
    for (int k = 0; k < K; ++k) {
      float xv = xs[r][k];
      al = fmaf(xv, Wl[k * 256 + j], al);
      ar = fmaf(xv, Wr[k * 256 + j], ar);
    }
    xl[(size_t)n * 256 + j] = al;
    xr[(size_t)n * 256 + j] = ar;
  }
}

// ---------------- batched weight split+transpose (both sides) ----------------
__global__ void k_wsplitb(const float* __restrict__ Wpl, const float* __restrict__ Wpr,
                          const float* __restrict__ Wll, const float* __restrict__ Wlr,
                          u16* __restrict__ Whp, u16* __restrict__ Wlp,
                          u16* __restrict__ Whl, u16* __restrict__ Wll_o) {
  int n = blockIdx.x & 511;
  int side = blockIdx.x >> 9;
  int col = n & 255;
  int k = threadIdx.x;
  const float* W = side == 0 ? (n < 256 ? Wpl : Wpr) : (n < 256 ? Wll : Wlr);
  float w = W[k * 256 + col];
  u16* Wh = side ? Whl : Whp;
  u16* Wlo = side ? Wll_o : Wlp;
  u16 hb = f2bf(w);
  Wh[n * 256 + k] = hb;
  Wlo[n * 256 + k] = f2bf(w - bf2f(hb));
}

// ---------------- dual GEMM via split-bf16 MFMA (unchanged core) ----------------
__global__ void __launch_bounds__(256, 2) k_mm_dual(
    const u16* __restrict__ Ahi, const u16* __restrict__ Alo,
    const u16* __restrict__ Bhi, const u16* __restrict__ Blo,
    float* __restrict__ XL, float* __restrict__ XR, int M) {
  __shared__ __align__(16) char smem[32768];
  char* sAh = smem;
  char* sAl = smem + 8192;
  char* sBh = smem + 16384;
  char* sBl = smem + 24576;
  const int t = threadIdx.x;
  const int rowBase = blockIdx.x * 128;
  const int j0 = blockIdx.y * 128;
  const int srow = t >> 1;
  const int h = t & 1;
  int gr = rowBase + srow;
  if (gr >= M) gr = M - 1;
  const size_t gaBase = (size_t)gr * 256 + h * 16;
  const size_t gbBase = (size_t)(j0 + srow) * 256 + h * 16;
  const int rb = srow * 64;
  const int sw0 = (((h * 2) + (srow >> 1)) & 3) * 16;
  const int sw1 = (((h * 2 + 1) + (srow >> 1)) & 3) * 16;
  const int lane = t & 63;
  const int wid = t >> 6;
  const int wm = (wid & 1) * 64;
  const int wn = (wid >> 1) * 64;
  const int kq = lane >> 4;
  const int mr = lane & 15;
  int offA[4], offB[4];
#pragma unroll
  for (int i = 0; i < 4; ++i) {
    int m = wm + i * 16 + mr;
    offA[i] = m * 64 + ((kq + (m >> 1)) & 3) * 16;
    int n = wn + i * 16 + mr;
    offB[i] = n * 64 + ((kq + (n >> 1)) & 3) * 16;
  }
  f32x4 acc[4][4] = {};
  for (int kt = 0; kt < 8; ++kt) {
    const int k0 = kt * 32;
    uint4 vah0 = *(const uint4*)(Ahi + gaBase + k0);
    uint4 vah1 = *(const uint4*)(Ahi + gaBase + k0 + 8);
    uint4 val0 = *(const uint4*)(Alo + gaBase + k0);
    uint4 val1 = *(const uint4*)(Alo + gaBase + k0 + 8);
    uint4 vbh0 = *(const uint4*)(Bhi + gbBase + k0);
    uint4 vbh1 = *(const uint4*)(Bhi + gbBase + k0 + 8);
    uint4 vbl0 = *(const uint4*)(Blo + gbBase + k0);
    uint4 vbl1 = *(const uint4*)(Blo + gbBase + k0 + 8);
    __syncthreads();
    *(uint4*)(sAh + rb + sw0) = vah0;
    *(uint4*)(sAh + rb + sw1) = vah1;
    *(uint4*)(sAl + rb + sw0) = val0;
    *(uint4*)(sAl + rb + sw1) = val1;
    *(uint4*)(sBh + rb + sw0) = vbh0;
    *(uint4*)(sBh + rb + sw1) = vbh1;
    *(uint4*)(sBl + rb + sw0) = vbl0;
    *(uint4*)(sBl + rb + sw1) = vbl1;
    __syncthreads();
    bf16x8 ah[4], al4[4], bh[4], bl4[4];
#pragma unroll
    for (int i = 0; i < 4; ++i) {
      ah[i] = *(const bf16x8*)(sAh + offA[i]);
      al4[i] = *(const bf16x8*)(sAl + offA[i]);
      bh[i] = *(const bf16x8*)(sBh + offB[i]);
      bl4[i] = *(const bf16x8*)(sBl + offB[i]);
    }
#pragma unroll
    for (int i = 0; i < 4; ++i)
#pragma unroll
      for (int j = 0; j < 4; ++j) {
        acc[i][j] = __builtin_amdgcn_mfma_f32_16x16x32_bf16(ah[i], bh[j], acc[i][j], 0, 0, 0);
        acc[i][j] = __builtin_amdgcn_mfma_f32_16x16x32_bf16(ah[i], bl4[j], acc[i][j], 0, 0, 0);
        acc[i][j] = __builtin_amdgcn_mfma_f32_16x16x32_bf16(al4[i], bh[j], acc[i][j], 0, 0, 0);
      }
  }
  float* cbase;
  int cb;
  if (blockIdx.y < 2) { cbase = XL; cb = j0; } else { cbase = XR; cb = j0 - 256; }
#pragma unroll
  for (int i = 0; i < 4; ++i) {
    int row0 = rowBase + wm + i * 16 + (lane >> 4) * 4;
#pragma unroll
    for (int j = 0; j < 4; ++j) {
      int col = cb + wn + j * 16 + mr;
#pragma unroll
      for (int r = 0; r < 4; ++r) {
        int row = row0 + r;
        if (row < M) cbase[(size_t)row * 256 + col] = acc[i][j][r];
      }
    }
  }
}

// ---------------- batched CSR build (both sides in one launch set) ----------------
__global__ void k_zero2b(int* __restrict__ a, int* __restrict__ b, int n) {
  int i = blockIdx.x * blockDim.x + threadIdx.x;
  if (i < n) { a[i] = 0; b[i] = 0; }
}

__global__ void k_histb(const int* __restrict__ eip, int Ep, const int* __restrict__ eil,
                        int El, int* __restrict__ cntp, int* __restrict__ cntl) {
  int e = blockIdx.x * blockDim.x + threadIdx.x;
  if (e < Ep) atomicAdd(&cntp[eip[Ep + e]], 1);
  else if (e < Ep + El) { int e2 = e - Ep; atomicAdd(&cntl[eil[El + e2]], 1); }
}

__global__ void k_scan1b(const int* __restrict__ cntp, int Np, const int* __restrict__ cntl,
                         int Nl, int nbp, int* __restrict__ offsp, int* __restrict__ offsl,
                         int* __restrict__ bsum) {
  __shared__ int s[256];
  int tid = threadIdx.x;
  int side = (blockIdx.x >= nbp) ? 1 : 0;
  int blk = side ? (blockIdx.x - nbp) : blockIdx.x;
  const int* cnt = side ? cntl : cntp;
  int* offs = side ? offsl : offsp;
  int N = side ? Nl : Np;
  int i = blk * 256 + tid;
  int v = (i < N) ? cnt[i] : 0;
  s[tid] = v;
  __syncthreads();
  for (int off = 1; off < 256; off <<= 1) {
    int t = 0;
    if (tid >= off) t = s[tid - off];
    __syncthreads();
    if (tid >= off) s[tid] += t;
    __syncthreads();
  }
  if (i < N) offs[i] = s[tid] - v;
  if (tid == 255) bsum[side * 256 + blk] = s[255];
}

__global__ void k_scan2b(int* __restrict__ bsum, int nbp, int nbl) {
  __shared__ int s[256];
  int side = blockIdx.x;
  int nb = side ? nbl : nbp;
  int* bs = bsum + side * 256;
  int tid = threadIdx.x;
  int v = (tid < nb) ? bs[tid] : 0;
  s[tid] = v;
  __syncthreads();
  for (int off = 1; off < 256; off <<= 1) {
    int t = 0;
    if (tid >= off) t = s[tid - off];
    __syncthreads();
    if (tid >= off) s[tid] += t;
    __syncthreads();
  }
  if (tid < nb) bs[tid] = s[tid] - v;
}

__global__ void k_scan3b(int* __restrict__ offsp, int Np, int* __restrict__ offsl, int Nl,
                         int nbp, const int* __restrict__ bsum) {
  int side = (blockIdx.x >= nbp) ? 1 : 0;
  int blk = side ? (blockIdx.x - nbp) : blockIdx.x;
  int* offs = side ? offsl : offsp;
  int N = side ? Nl : Np;
  int i = blk * 256 + threadIdx.x;
  if (i < N) offs[i] += bsum[side * 256 + blk];
}

__global__ void k_fillb(const int* __restrict__ eip, int Ep, const int* __restrict__ eil,
                        int El, const int* __restrict__ offsp, const int* __restrict__ offsl,
                        int* __restrict__ curp, int* __restrict__ curl,
                        int* __restrict__ csrp, int* __restrict__ csrl) {
  int e = blockIdx.x * blockDim.x + threadIdx.x;
  if (e < Ep) {
    int d = eip[Ep + e];
    int pos = offsp[d] + atomicAdd(&curp[d], 1);
    csrp[pos] = eip[e];
  } else if (e < Ep + El) {
    int e2 = e - Ep;
    int d = eil[El + e2];
    int pos = offsl[d] + atomicAdd(&curl[d], 1);
    csrl[pos] = eil[e2];
  }
}

// ---------------- GATv2 aggregation: wave/dst, 2-way unrolled online softmax ----------------
template <int H, bool SPLIT>
__global__ void k_gat_gather(const float* __restrict__ xl, const float* __restrict__ xr,
                             const int* __restrict__ csr_src, const int* __restrict__ offs,
                             const int* __restrict__ cnt, const float* __restrict__ att,
                             const float* __restrict__ bias, int N,
                             float* __restrict__ outf, u16* __restrict__ ohi,
                             u16* __restrict__ olo) {
  int d = blockIdx.x * 4 + (threadIdx.x >> 6);
  if (d >= N) return;
  int lane = threadIdx.x & 63;
  const float4 rd = *(const float4*)&xr[(size_t)d * 256 + lane * 4];
  const float4 wa = *(const float4*)&att[lane * 4];
  const float4 xd = *(const float4*)&xl[(size_t)d * 256 + lane * 4];
  float p = LR_GAT(xd.x + rd.x) * wa.x + LR_GAT(xd.y + rd.y) * wa.y +
            LR_GAT(xd.z + rd.z) * wa.z + LR_GAT(xd.w + rd.w) * wa.w;
#pragma unroll
  for (int off = 1; off <= (H == 2 ? 16 : 32); off <<= 1) p += __shfl_xor(p, off, 64);
  // state A seeded with self-loop; state B empty
  float mA = p, lA = 1.f, mB = -INFINITY, lB = 0.f;
  float4 accA = xd;
  float4 accB = make_float4(0.f, 0.f, 0.f, 0.f);
  const int o0 = offs[d];
  const int c = cnt[d];
  int s0 = 0, s1 = 0;
  if (c > 0) s0 = csr_src[o0];
  if (c > 1) s1 = csr_src[o0 + 1];
  int j = 0;
  for (; j + 1 < c; j += 2) {
    int t0 = (j + 2 < c) ? csr_src[o0 + j + 2] : 0;
    int t1 = (j + 3 < c) ? csr_src[o0 + j + 3] : 0;
    float4 a0 = *(const float4*)&xl[(size_t)s0 * 256 + lane * 4];
    float4 a1 = *(const float4*)&xl[(size_t)s1 * 256 + lane * 4];
    float q0 = LR_GAT(a0.x + rd.x) * wa.x + LR_GAT(a0.y + rd.y) * wa.y +
               LR_GAT(a0.z + rd.z) * wa.z + LR_GAT(a0.w + rd.w) * wa.w;
    float q1 = LR_GAT(a1.x + rd.x) * wa.x + LR_GAT(a1.y + rd.y) * wa.y +
               LR_GAT(a1.z + rd.z) * wa.z + LR_GAT(a1.w + rd.w) * wa.w;
#pragma unroll
    for (int off = 1; off <= (H == 2 ? 16 : 32); off <<= 1) {
      q0 += __shfl_xor(q0, off, 64);
      q1 += __shfl_xor(q1, off, 64);
    }
    {
      float mn = fmaxf(mA, q0);
      float sc = __expf(mA - mn), w = __expf(q0 - mn);
      lA = lA * sc + w;
      accA.x = accA.x * sc + w * a0.x;
      accA.y = accA.y * sc + w * a0.y;
      accA.z = accA.z * sc + w * a0.z;
      accA.w = accA.w * sc + w * a0.w;
      mA = mn;
    }
    {
      float mn = fmaxf(mB, q1);
      float sc = __expf(mB - mn), w = __expf(q1 - mn);
      lB = lB * sc + w;
      accB.x = accB.x * sc + w * a1.x;
      accB.y = accB.y * sc + w * a1.y;
      accB.z = accB.z * sc + w * a1.z;
      accB.w = accB.w * sc + w * a1.w;
      mB = mn;
    }
    s0 = t0;
    s1 = t1;
  }
  if (j < c) {  // odd tail -> state A
    float4 a0 = *(const float4*)&xl[(size_t)s0 * 256 + lane * 4];
    float q0 = LR_GAT(a0.x + rd.x) * wa.x + LR_GAT(a0.y + rd.y) * wa.y +
               LR_GAT(a0.z + rd.z) * wa.z + LR_GAT(a0.w + rd.w) * wa.w;
#pragma unroll
    for (int off = 1; off <= (H == 2 ? 16 : 32); off <<= 1) q0 += __shfl_xor(q0, off, 64);
    float mn = fmaxf(mA, q0);
    float sc = __expf(mA - mn), w = __expf(q0 - mn);
    lA = lA * sc + w;
    accA.x = accA.x * sc + w * a0.x;
    accA.y = accA.y * sc + w * a0.y;
    accA.z = accA.z * sc + w * a0.z;
    accA.w = accA.w * sc + w * a0.w;
    mA = mn;
  }
  // merge B into A
  {
    float mn = fmaxf(mA, mB);
    float eA = __expf(mA - mn), eB = __expf(mB - mn);
    lA = lA * eA + lB * eB;
    accA.x = accA.x * eA + accB.x * eB;
    accA.y = accA.y * eA + accB.y * eB;
    accA.z = accA.z * eA + accB.z * eB;
    accA.w = accA.w * eA + accB.w * eB;
  }
  float inv = 1.f / lA;
  const float4 b4 = *(const float4*)&bias[lane * 4];
  float4 o;
  o.x = accA.x * inv + b4.x;
  o.y = accA.y * inv + b4.y;
  o.z = accA.z * inv + b4.z;
  o.w = accA.w * inv + b4.w;
  if (SPLIT) {
    ushort4 hv, lv;
    hv.x = f2bf(o.x); lv.x = f2bf(o.x - bf2f(hv.x));
    hv.y = f2bf(o.y); lv.y = f2bf(o.y - bf2f(hv.y));
    hv.z = f2bf(o.z); lv.z = f2bf(o.z - bf2f(hv.z));
    hv.w = f2bf(o.w); lv.w = f2bf(o.w - bf2f(hv.w));
    *(ushort4*)&ohi[(size_t)d * 256 + lane * 4] = hv;
    *(ushort4*)&olo[(size_t)d * 256 + lane * 4] = lv;
  } else {
    *(float4*)&outf[(size_t)d * 256 + lane * 4] = o;
  }
}

// ---------------- mean pool over sorted batch ids ----------------
__global__ void k_pool(const float* __restrict__ x, const int* __restrict__ batch, int N,
                       float* __restrict__ pool) {
  int b = blockIdx.x;
  int j = threadIdx.x;
  __shared__ int sss, sse;
  if (j == 0) {
    int lo = 0, hi = N;
    while (lo < hi) { int mid = (lo + hi) >> 1; if (batch[mid] < b) lo = mid + 1; else hi = mid; }
    sss = lo;
    lo = 0; hi = N;
    while (lo < hi) { int mid = (lo + hi) >> 1; if (batch[mid] < b + 1) lo = mid + 1; else hi = mid; }
    sse = lo;
  }
  __syncthreads();
  float acc = 0.f;
  for (int n = sss; n < sse; ++n) acc += x[(size_t)n * 256 + j];
  float cntf = (float)(sse - sss);
  pool[b * 256 + j] = acc / fmaxf(cntf, 1.f);
}

// ---------------- fused head ----------------
__global__ void k_head(const float* __restrict__ pp, const float* __restrict__ lp,
                       const float* __restrict__ Wv, const float* __restrict__ bv,
                       const float* __restrict__ Wo, const float* __restrict__ bo,
                       const float* __restrict__ fc1w, const float* __restrict__ fc1b,
                       const float* __restrict__ lng, const float* __restrict__ lnb,
                       const float* __restrict__ fc2w, const float* __restrict__ fc2b,
                       float* __restrict__ out) {
  int b = blockIdx.x;
  int j = threadIdx.x;
  __shared__ float lxs[256];
  __shared__ float vbuf[256];
  __shared__ float comb[512];
  __shared__ float r1[256], r2[256];
  __shared__ float smu, srs;
  lxs[j] = lp[b * 256 + j];
  comb[j] = pp[b * 256 + j];
  __syncthreads();
  float v = bv[j];
  for (int k = 0; k < 256; ++k) v = fmaf(lxs[k], Wv[k * 256 + j], v);
  vbuf[j] = v;
  __syncthreads();
  float at = bo[j];
  for (int k = 0; k < 256; ++k) at = fmaf(vbuf[k], Wo[k * 256 + j], at);
  comb[256 + j] = at;
  __syncthreads();
  float h = fc1b[j];
  for (int k = 0; k < 512; ++k) h = fmaf(comb[k], fc1w[k * 256 + j], h);
  r1[j] = h;
  r2[j] = h * h;
  __syncthreads();
  for (int off = 128; off > 0; off >>= 1) {
    if (j < off) { r1[j] += r1[j + off]; r2[j] += r2[j + off]; }
    __syncthreads();
  }
  if (j == 0) {
    float mu = r1[0] / 256.f;
    float var = r2[0] / 256.f - mu * mu;
    smu = mu;
    srs = 1.f / sqrtf(var + 1e-5f);
  }
  __syncthreads();
  float hn = (h - smu) * srs * lng[j] + lnb[j];
  hn = hn > 0.f ? hn : 0.01f * hn;
  r1[j] = hn * fc2w[j];
  __syncthreads();
  for (int off = 128; off > 0; off >>= 1) {
    if (j < off) r1[j] += r1[j + off];
    __syncthreads();
  }
  if (j == 0) out[b] = r1[0] + fc2b[0];
}

// ---------------- per-side heavy pipeline ----------------
static void run_side(const float* x, int K, int N,
                     const float* W1l, const float* W1r, const float* att1, const float* b1,
                     const float* att2, const float* b2,
                     const int* batch, float* pool,
                     float* XL, float* XR, float* A2, u16* Ahi, u16* Alo,
                     const u16* Wth, const u16* Wtl,
                     const int* cnt, const int* offs, const int* csr_src,
                     hipStream_t st) {
  const int gb = (N + 3) / 4;
  k_lin_small<<<(N + 7) / 8, 256, 0, st>>>(x, W1l, W1r, N, K, XL, XR);
  k_gat_gather<2, true><<<gb, 256, 0, st>>>(XL, XR, csr_src, offs, cnt, att1, b1, N,
                                            nullptr, Ahi, Alo);
  k_mm_dual<<<dim3((N + 127) / 128, 4), 256, 0, st>>>(Ahi, Alo, Wth, Wtl, XL, XR, N);
  k_gat_gather<1, false><<<gb, 256, 0, st>>>(XL, XR, csr_src, offs, cnt, att2, b2, N,
                                             A2, nullptr, nullptr);
  k_pool<<<256, 256, 0, st>>>(A2, batch, N, pool);
}

extern "C" void kernel_launch(void* const* d_in, const int* in_sizes, int n_in,
                              void* d_out, int out_size, void* d_ws, size_t ws_size,
                              hipStream_t stream) {
  const float* px = (const float*)d_in[0];
  const float* lx = (const float*)d_in[1];
  const int* pei = (const int*)d_in[2];
  const int* lei = (const int*)d_in[3];
  const int* pb = (const int*)d_in[4];
  const int* lb = (const int*)d_in[5];
  const float* p1_Wl = (const float*)d_in[6];
  const float* p1_Wr = (const float*)d_in[7];
  const float* p1_att = (const float*)d_in[8];
  const float* p1_b = (const float*)d_in[9];
  const float* p2_Wl = (const float*)d_in[10];
  const float* p2_Wr = (const float*)d_in[11];
  const float* p2_att = (const float*)d_in[12];
  const float* p2_b = (const float*)d_in[13];
  const float* l1_Wl = (const float*)d_in[14];
  const float* l1_Wr = (const float*)d_in[15];
  const float* l1_att = (const float*)d_in[16];
  const float* l1_b = (const float*)d_in[17];
  const float* l2_Wl = (const float*)d_in[18];
  const float* l2_Wr = (const float*)d_in[19];
  const float* l2_att = (const float*)d_in[20];
  const float* l2_b = (const float*)d_in[21];
  const float* Wv = (const float*)d_in[26];
  const float* bv = (const float*)d_in[27];
  const float* Wo = (const float*)d_in[28];
  const float* bo = (const float*)d_in[29];
  const float* fc1w = (const float*)d_in[30];
  const float* fc1b = (const float*)d_in[31];
  const float* lng = (const float*)d_in[32];
  const float* lnb = (const float*)d_in[33];
  const float* fc2w = (const float*)d_in[34];
  const float* fc2b = (const float*)d_in[35];

  const int NPn = in_sizes[4];
  const int NLn = in_sizes[5];
  const int EPe = in_sizes[2] / 2;
  const int ELe = in_sizes[3] / 2;
  const int KP = in_sizes[0] / NPn;
  const int KL = in_sizes[1] / NLn;

  const int Nmax = NPn > NLn ? NPn : NLn;
  const int Emax = EPe > ELe ? EPe : ELe;
  size_t NF = (size_t)Nmax * 256;

  float* XL = (float*)d_ws;
  float* XR = XL + NF;
  u16* Ahi = (u16*)(XR + NF);
  u16* Alo = Ahi + NF;
  float* A2 = (float*)Ahi;  // aliases Ahi/Alo after GEMM consumed them
  u16* Wth = Alo + NF;          // 2 sides x 512*256
  u16* Wtl = Wth + 2 * 512 * 256;
  float* PP = (float*)(Wtl + 2 * 512 * 256);
  float* LP = PP + 256 * 256;
  int* cnt = (int*)(LP + 256 * 256);  // 2*Nmax
  int* cur = cnt + 2 * (size_t)Nmax;
  int* offs = cur + 2 * (size_t)Nmax;
  int* bsum = offs + 2 * (size_t)Nmax;  // 512
  int* csr = bsum + 512;                // 2*Emax
  int* cnt_l = cnt + Nmax;
  int* cur_l = cur + Nmax;
  int* offs_l = offs + Nmax;
  int* csr_l = csr + Emax;

  const int nbp = (NPn + 255) / 256;
  const int nbl = (NLn + 255) / 256;

  // batched CSR build for both sides
  k_zero2b<<<(2 * Nmax + 255) / 256, 256, 0, stream>>>(cnt, cur, 2 * Nmax);
  k_histb<<<(EPe + ELe + 255) / 256, 256, 0, stream>>>(pei, EPe, lei, ELe, cnt, cnt_l);
  k_scan1b<<<nbp + nbl, 256, 0, stream>>>(cnt, NPn, cnt_l, NLn, nbp, offs, offs_l, bsum);
  k_scan2b<<<2, 256, 0, stream>>>(bsum, nbp, nbl);
  k_scan3b<<<nbp + nbl, 256, 0, stream>>>(offs, NPn, offs_l, NLn, nbp, bsum);
  k_fillb<<<(EPe + ELe + 255) / 256, 256, 0, stream>>>(pei, EPe, lei, ELe, offs, offs_l,
                                                       cur, cur_l, csr, csr_l);
  // batched weight split for both sides' layer-2
  k_wsplitb<<<1024, 256, 0, stream>>>(p2_Wl, p2_Wr, l2_Wl, l2_Wr,
                                      Wth, Wtl, Wth + 512 * 256, Wtl + 512 * 256);

  run_side(px, KP, NPn, p1_Wl, p1_Wr, p1_att, p1_b, p2_att, p2_b, pb, PP,
           XL, XR, A2, Ahi, Alo, Wth, Wtl, cnt, offs, csr, stream);
  run_side(lx, KL, NLn, l1_Wl, l1_Wr, l1_att, l1_b, l2_att, l2_b, lb, LP,
           XL, XR, A2, Ahi, Alo, Wth + 512 * 256, Wtl + 512 * 256, cnt_l, offs_l, csr_l,
           stream);

  k_head<<<256, 256, 0, stream>>>(PP, LP, Wv, bv, Wo, bo, fc1w, fc1b, lng, lnb, fc2w, fc2b,
                                  (float*)d_out);
  (void)n_in; (void)out_size; (void)ws_size;
}

// Round 5
// 735.138 us; speedup vs baseline: 10.0347x; 1.1715x over previous
//
#include <hip/hip_runtime.h>
#include <math.h>

#define LR_GAT(x) ((x) > 0.f ? (x) : 0.2f * (x))

typedef unsigned short u16;
typedef __attribute__((ext_vector_type(8))) short bf16x8;
typedef __attribute__((ext_vector_type(4))) float f32x4;

__device__ inline u16 f2bf(float x) {
  unsigned int u = __float_as_uint(x);
  u += 0x7fffu + ((u >> 16) & 1u);
  return (u16)(u >> 16);
}
__device__ inline float bf2f(u16 h) {
  return __uint_as_float(((unsigned int)h) << 16);
}

// ---------------- layer-1 transform: 8 nodes/block, bf16 outputs ----------------
__global__ void k_lin_small(const float* __restrict__ x, const float* __restrict__ Wl,
                            const float* __restrict__ Wr, int N, int K,
                            u16* __restrict__ xlh, u16* __restrict__ xrh) {
  int base = blockIdx.x * 8;
  int j = threadIdx.x;
  __shared__ float xs[8][16];
  int tot = 8 * K;
  for (int i = j; i < tot; i += 256) {
    int r = i / K, k = i - r * K;
    if (base + r < N) xs[r][k] = x[(size_t)(base + r) * K + k];
  }
  __syncthreads();
#pragma unroll
  for (int r = 0; r < 8; ++r) {
    int n = base + r;
    if (n >= N) break;
    float al = 0.f, ar = 0.f;
    for (int k = 0; k < K; ++k) {
      float xv = xs[r][k];
      al = fmaf(xv, Wl[k * 256 + j], al);
      ar = fmaf(xv, Wr[k * 256 + j], ar);
    }
    xlh[(size_t)n * 256 + j] = f2bf(al);
    xrh[(size_t)n * 256 + j] = f2bf(ar);
  }
}

// ---------------- batched weight split+transpose (both sides) ----------------
__global__ void k_wsplitb(const float* __restrict__ Wpl, const float* __restrict__ Wpr,
                          const float* __restrict__ Wll, const float* __restrict__ Wlr,
                          u16* __restrict__ Whp, u16* __restrict__ Wlp,
                          u16* __restrict__ Whl, u16* __restrict__ Wll_o) {
  int n = blockIdx.x & 511;
  int side = blockIdx.x >> 9;
  int col = n & 255;
  int k = threadIdx.x;
  const float* W = side == 0 ? (n < 256 ? Wpl : Wpr) : (n < 256 ? Wll : Wlr);
  float w = W[k * 256 + col];
  u16* Wh = side ? Whl : Whp;
  u16* Wlo = side ? Wll_o : Wlp;
  u16 hb = f2bf(w);
  Wh[n * 256 + k] = hb;
  Wlo[n * 256 + k] = f2bf(w - bf2f(hb));
}

// ---------------- dual GEMM via split-bf16 MFMA; bf16 outputs ----------------
__global__ void __launch_bounds__(256, 2) k_mm_dual(
    const u16* __restrict__ Ahi, const u16* __restrict__ Alo,
    const u16* __restrict__ Bhi, const u16* __restrict__ Blo,
    u16* __restrict__ XLh, u16* __restrict__ XRh, int M) {
  __shared__ __align__(16) char smem[32768];
  char* sAh = smem;
  char* sAl = smem + 8192;
  char* sBh = smem + 16384;
  char* sBl = smem + 24576;
  const int t = threadIdx.x;
  const int rowBase = blockIdx.x * 128;
  const int j0 = blockIdx.y * 128;
  const int srow = t >> 1;
  const int h = t & 1;
  int gr = rowBase + srow;
  if (gr >= M) gr = M - 1;
  const size_t gaBase = (size_t)gr * 256 + h * 16;
  const size_t gbBase = (size_t)(j0 + srow) * 256 + h * 16;
  const int rb = srow * 64;
  const int sw0 = (((h * 2) + (srow >> 1)) & 3) * 16;
  const int sw1 = (((h * 2 + 1) + (srow >> 1)) & 3) * 16;
  const int lane = t & 63;
  const int wid = t >> 6;
  const int wm = (wid & 1) * 64;
  const int wn = (wid >> 1) * 64;
  const int kq = lane >> 4;
  const int mr = lane & 15;
  int offA[4], offB[4];
#pragma unroll
  for (int i = 0; i < 4; ++i) {
    int m = wm + i * 16 + mr;
    offA[i] = m * 64 + ((kq + (m >> 1)) & 3) * 16;
    int n = wn + i * 16 + mr;
    offB[i] = n * 64 + ((kq + (n >> 1)) & 3) * 16;
  }
  f32x4 acc[4][4] = {};
  for (int kt = 0; kt < 8; ++kt) {
    const int k0 = kt * 32;
    uint4 vah0 = *(const uint4*)(Ahi + gaBase + k0);
    uint4 vah1 = *(const uint4*)(Ahi + gaBase + k0 + 8);
    uint4 val0 = *(const uint4*)(Alo + gaBase + k0);
    uint4 val1 = *(const uint4*)(Alo + gaBase + k0 + 8);
    uint4 vbh0 = *(const uint4*)(Bhi + gbBase + k0);
    uint4 vbh1 = *(const uint4*)(Bhi + gbBase + k0 + 8);
    uint4 vbl0 = *(const uint4*)(Blo + gbBase + k0);
    uint4 vbl1 = *(const uint4*)(Blo + gbBase + k0 + 8);
    __syncthreads();
    *(uint4*)(sAh + rb + sw0) = vah0;
    *(uint4*)(sAh + rb + sw1) = vah1;
    *(uint4*)(sAl + rb + sw0) = val0;
    *(uint4*)(sAl + rb + sw1) = val1;
    *(uint4*)(sBh + rb + sw0) = vbh0;
    *(uint4*)(sBh + rb + sw1) = vbh1;
    *(uint4*)(sBl + rb + sw0) = vbl0;
    *(uint4*)(sBl + rb + sw1) = vbl1;
    __syncthreads();
    bf16x8 ah[4], al4[4], bh[4], bl4[4];
#pragma unroll
    for (int i = 0; i < 4; ++i) {
      ah[i] = *(const bf16x8*)(sAh + offA[i]);
      al4[i] = *(const bf16x8*)(sAl + offA[i]);
      bh[i] = *(const bf16x8*)(sBh + offB[i]);
      bl4[i] = *(const bf16x8*)(sBl + offB[i]);
    }
#pragma unroll
    for (int i = 0; i < 4; ++i)
#pragma unroll
      for (int j = 0; j < 4; ++j) {
        acc[i][j] = __builtin_amdgcn_mfma_f32_16x16x32_bf16(ah[i], bh[j], acc[i][j], 0, 0, 0);
        acc[i][j] = __builtin_amdgcn_mfma_f32_16x16x32_bf16(ah[i], bl4[j], acc[i][j], 0, 0, 0);
        acc[i][j] = __builtin_amdgcn_mfma_f32_16x16x32_bf16(al4[i], bh[j], acc[i][j], 0, 0, 0);
      }
  }
  u16* cbase;
  int cb;
  if (blockIdx.y < 2) { cbase = XLh; cb = j0; } else { cbase = XRh; cb = j0 - 256; }
#pragma unroll
  for (int i = 0; i < 4; ++i) {
    int row0 = rowBase + wm + i * 16 + (lane >> 4) * 4;
#pragma unroll
    for (int j = 0; j < 4; ++j) {
      int col = cb + wn + j * 16 + mr;
#pragma unroll
      for (int r = 0; r < 4; ++r) {
        int row = row0 + r;
        if (row < M) cbase[(size_t)row * 256 + col] = f2bf(acc[i][j][r]);
      }
    }
  }
}

// ---------------- batched CSR build ----------------
__global__ void k_zero2b(int* __restrict__ a, int* __restrict__ b, int n) {
  int i = blockIdx.x * blockDim.x + threadIdx.x;
  if (i < n) { a[i] = 0; b[i] = 0; }
}

__global__ void k_histb(const int* __restrict__ eip, int Ep, const int* __restrict__ eil,
                        int El, int* __restrict__ cntp, int* __restrict__ cntl) {
  int e = blockIdx.x * blockDim.x + threadIdx.x;
  if (e < Ep) atomicAdd(&cntp[eip[Ep + e]], 1);
  else if (e < Ep + El) { int e2 = e - Ep; atomicAdd(&cntl[eil[El + e2]], 1); }
}

__global__ void k_scan1b(const int* __restrict__ cntp, int Np, const int* __restrict__ cntl,
                         int Nl, int nbp, int* __restrict__ offsp, int* __restrict__ offsl,
                         int* __restrict__ bsum) {
  __shared__ int s[256];
  int tid = threadIdx.x;
  int side = (blockIdx.x >= nbp) ? 1 : 0;
  int blk = side ? (blockIdx.x - nbp) : blockIdx.x;
  const int* cnt = side ? cntl : cntp;
  int* offs = side ? offsl : offsp;
  int N = side ? Nl : Np;
  int i = blk * 256 + tid;
  int v = (i < N) ? cnt[i] : 0;
  s[tid] = v;
  __syncthreads();
  for (int off = 1; off < 256; off <<= 1) {
    int t = 0;
    if (tid >= off) t = s[tid - off];
    __syncthreads();
    if (tid >= off) s[tid] += t;
    __syncthreads();
  }
  if (i < N) offs[i] = s[tid] - v;
  if (tid == 255) bsum[side * 256 + blk] = s[255];
}

__global__ void k_scan2b(int* __restrict__ bsum, int nbp, int nbl) {
  __shared__ int s[256];
  int side = blockIdx.x;
  int nb = side ? nbl : nbp;
  int* bs = bsum + side * 256;
  int tid = threadIdx.x;
  int v = (tid < nb) ? bs[tid] : 0;
  s[tid] = v;
  __syncthreads();
  for (int off = 1; off < 256; off <<= 1) {
    int t = 0;
    if (tid >= off) t = s[tid - off];
    __syncthreads();
    if (tid >= off) s[tid] += t;
    __syncthreads();
  }
  if (tid < nb) bs[tid] = s[tid] - v;
}

__global__ void k_scan3b(int* __restrict__ offsp, int Np, int* __restrict__ offsl, int Nl,
                         int nbp, const int* __restrict__ bsum) {
  int side = (blockIdx.x >= nbp) ? 1 : 0;
  int blk = side ? (blockIdx.x - nbp) : blockIdx.x;
  int* offs = side ? offsl : offsp;
  int N = side ? Nl : Np;
  int i = blk * 256 + threadIdx.x;
  if (i < N) offs[i] += bsum[side * 256 + blk];
}

__global__ void k_fillb(const int* __restrict__ eip, int Ep, const int* __restrict__ eil,
                        int El, const int* __restrict__ offsp, const int* __restrict__ offsl,
                        int* __restrict__ curp, int* __restrict__ curl,
                        int* __restrict__ csrp, int* __restrict__ csrl) {
  int e = blockIdx.x * blockDim.x + threadIdx.x;
  if (e < Ep) {
    int d = eip[Ep + e];
    int pos = offsp[d] + atomicAdd(&curp[d], 1);
    csrp[pos] = eip[e];
  } else if (e < Ep + El) {
    int e2 = e - Ep;
    int d = eil[El + e2];
    int pos = offsl[d] + atomicAdd(&curl[d], 1);
    csrl[pos] = eil[e2];
  }
}

// ---------------- GATv2 aggregation: bf16 inputs, fp32 state, 2-way unroll ----------------
__device__ inline float4 ld_bf4(const u16* p) {
  ushort4 v = *(const ushort4*)p;
  return make_float4(bf2f(v.x), bf2f(v.y), bf2f(v.z), bf2f(v.w));
}

template <int H, bool SPLIT>
__global__ void k_gat_gather(const u16* __restrict__ xlh, const u16* __restrict__ xrh,
                             const int* __restrict__ csr_src, const int* __restrict__ offs,
                             const int* __restrict__ cnt, const float* __restrict__ att,
                             const float* __restrict__ bias, int N,
                             float* __restrict__ outf, u16* __restrict__ ohi,
                             u16* __restrict__ olo) {
  int d = blockIdx.x * 4 + (threadIdx.x >> 6);
  if (d >= N) return;
  int lane = threadIdx.x & 63;
  const float4 rd = ld_bf4(&xrh[(size_t)d * 256 + lane * 4]);
  const float4 wa = *(const float4*)&att[lane * 4];
  const float4 xd = ld_bf4(&xlh[(size_t)d * 256 + lane * 4]);
  float p = LR_GAT(xd.x + rd.x) * wa.x + LR_GAT(xd.y + rd.y) * wa.y +
            LR_GAT(xd.z + rd.z) * wa.z + LR_GAT(xd.w + rd.w) * wa.w;
#pragma unroll
  for (int off = 1; off <= (H == 2 ? 16 : 32); off <<= 1) p += __shfl_xor(p, off, 64);
  float mA = p, lA = 1.f, mB = -INFINITY, lB = 0.f;
  float4 accA = xd;
  float4 accB = make_float4(0.f, 0.f, 0.f, 0.f);
  const int o0 = offs[d];
  const int c = cnt[d];
  int s0 = 0, s1 = 0;
  if (c > 0) s0 = csr_src[o0];
  if (c > 1) s1 = csr_src[o0 + 1];
  int j = 0;
  for (; j + 1 < c; j += 2) {
    int t0 = (j + 2 < c) ? csr_src[o0 + j + 2] : 0;
    int t1 = (j + 3 < c) ? csr_src[o0 + j + 3] : 0;
    float4 a0 = ld_bf4(&xlh[(size_t)s0 * 256 + lane * 4]);
    float4 a1 = ld_bf4(&xlh[(size_t)s1 * 256 + lane * 4]);
    float q0 = LR_GAT(a0.x + rd.x) * wa.x + LR_GAT(a0.y + rd.y) * wa.y +
               LR_GAT(a0.z + rd.z) * wa.z + LR_GAT(a0.w + rd.w) * wa.w;
    float q1 = LR_GAT(a1.x + rd.x) * wa.x + LR_GAT(a1.y + rd.y) * wa.y +
               LR_GAT(a1.z + rd.z) * wa.z + LR_GAT(a1.w + rd.w) * wa.w;
#pragma unroll
    for (int off = 1; off <= (H == 2 ? 16 : 32); off <<= 1) {
      q0 += __shfl_xor(q0, off, 64);
      q1 += __shfl_xor(q1, off, 64);
    }
    {
      float mn = fmaxf(mA, q0);
      float sc = __expf(mA - mn), w = __expf(q0 - mn);
      lA = lA * sc + w;
      accA.x = accA.x * sc + w * a0.x;
      accA.y = accA.y * sc + w * a0.y;
      accA.z = accA.z * sc + w * a0.z;
      accA.w = accA.w * sc + w * a0.w;
      mA = mn;
    }
    {
      float mn = fmaxf(mB, q1);
      float sc = __expf(mB - mn), w = __expf(q1 - mn);
      lB = lB * sc + w;
      accB.x = accB.x * sc + w * a1.x;
      accB.y = accB.y * sc + w * a1.y;
      accB.z = accB.z * sc + w * a1.z;
      accB.w = accB.w * sc + w * a1.w;
      mB = mn;
    }
    s0 = t0;
    s1 = t1;
  }
  if (j < c) {
    float4 a0 = ld_bf4(&xlh[(size_t)s0 * 256 + lane * 4]);
    float q0 = LR_GAT(a0.x + rd.x) * wa.x + LR_GAT(a0.y + rd.y) * wa.y +
               LR_GAT(a0.z + rd.z) * wa.z + LR_GAT(a0.w + rd.w) * wa.w;
#pragma unroll
    for (int off = 1; off <= (H == 2 ? 16 : 32); off <<= 1) q0 += __shfl_xor(q0, off, 64);
    float mn = fmaxf(mA, q0);
    float sc = __expf(mA - mn), w = __expf(q0 - mn);
    lA = lA * sc + w;
    accA.x = accA.x * sc + w * a0.x;
    accA.y = accA.y * sc + w * a0.y;
    accA.z = accA.z * sc + w * a0.z;
    accA.w = accA.w * sc + w * a0.w;
    mA = mn;
  }
  {
    float mn = fmaxf(mA, mB);
    float eA = __expf(mA - mn), eB = __expf(mB - mn);
    lA = lA * eA + lB * eB;
    accA.x = accA.x * eA + accB.x * eB;
    accA.y = accA.y * eA + accB.y * eB;
    accA.z = accA.z * eA + accB.z * eB;
    accA.w = accA.w * eA + accB.w * eB;
  }
  float inv = 1.f / lA;
  const float4 b4 = *(const float4*)&bias[lane * 4];
  float4 o;
  o.x = accA.x * inv + b4.x;
  o.y = accA.y * inv + b4.y;
  o.z = accA.z * inv + b4.z;
  o.w = accA.w * inv + b4.w;
  if (SPLIT) {
    ushort4 hv, lv;
    hv.x = f2bf(o.x); lv.x = f2bf(o.x - bf2f(hv.x));
    hv.y = f2bf(o.y); lv.y = f2bf(o.y - bf2f(hv.y));
    hv.z = f2bf(o.z); lv.z = f2bf(o.z - bf2f(hv.z));
    hv.w = f2bf(o.w); lv.w = f2bf(o.w - bf2f(hv.w));
    *(ushort4*)&ohi[(size_t)d * 256 + lane * 4] = hv;
    *(ushort4*)&olo[(size_t)d * 256 + lane * 4] = lv;
  } else {
    *(float4*)&outf[(size_t)d * 256 + lane * 4] = o;
  }
}

// ---------------- mean pool over sorted batch ids ----------------
__global__ void k_pool(const float* __restrict__ x, const int* __restrict__ batch, int N,
                       float* __restrict__ pool) {
  int b = blockIdx.x;
  int j = threadIdx.x;
  __shared__ int sss, sse;
  if (j == 0) {
    int lo = 0, hi = N;
    while (lo < hi) { int mid = (lo + hi) >> 1; if (batch[mid] < b) lo = mid + 1; else hi = mid; }
    sss = lo;
    lo = 0; hi = N;
    while (lo < hi) { int mid = (lo + hi) >> 1; if (batch[mid] < b + 1) lo = mid + 1; else hi = mid; }
    sse = lo;
  }
  __syncthreads();
  float acc = 0.f;
  for (int n = sss; n < sse; ++n) acc += x[(size_t)n * 256 + j];
  float cntf = (float)(sse - sss);
  pool[b * 256 + j] = acc / fmaxf(cntf, 1.f);
}

// ---------------- fused head ----------------
__global__ void k_head(const float* __restrict__ pp, const float* __restrict__ lp,
                       const float* __restrict__ Wv, const float* __restrict__ bv,
                       const float* __restrict__ Wo, const float* __restrict__ bo,
                       const float* __restrict__ fc1w, const float* __restrict__ fc1b,
                       const float* __restrict__ lng, const float* __restrict__ lnb,
                       const float* __restrict__ fc2w, const float* __restrict__ fc2b,
                       float* __restrict__ out) {
  int b = blockIdx.x;
  int j = threadIdx.x;
  __shared__ float lxs[256];
  __shared__ float vbuf[256];
  __shared__ float comb[512];
  __shared__ float r1[256], r2[256];
  __shared__ float smu, srs;
  lxs[j] = lp[b * 256 + j];
  comb[j] = pp[b * 256 + j];
  __syncthreads();
  float v = bv[j];
  for (int k = 0; k < 256; ++k) v = fmaf(lxs[k], Wv[k * 256 + j], v);
  vbuf[j] = v;
  __syncthreads();
  float at = bo[j];
  for (int k = 0; k < 256; ++k) at = fmaf(vbuf[k], Wo[k * 256 + j], at);
  comb[256 + j] = at;
  __syncthreads();
  float h = fc1b[j];
  for (int k = 0; k < 512; ++k) h = fmaf(comb[k], fc1w[k * 256 + j], h);
  r1[j] = h;
  r2[j] = h * h;
  __syncthreads();
  for (int off = 128; off > 0; off >>= 1) {
    if (j < off) { r1[j] += r1[j + off]; r2[j] += r2[j + off]; }
    __syncthreads();
  }
  if (j == 0) {
    float mu = r1[0] / 256.f;
    float var = r2[0] / 256.f - mu * mu;
    smu = mu;
    srs = 1.f / sqrtf(var + 1e-5f);
  }
  __syncthreads();
  float hn = (h - smu) * srs * lng[j] + lnb[j];
  hn = hn > 0.f ? hn : 0.01f * hn;
  r1[j] = hn * fc2w[j];
  __syncthreads();
  for (int off = 128; off > 0; off >>= 1) {
    if (j < off) r1[j] += r1[j + off];
    __syncthreads();
  }
  if (j == 0) out[b] = r1[0] + fc2b[0];
}

// ---------------- per-side heavy pipeline ----------------
static void run_side(const float* x, int K, int N,
                     const float* W1l, const float* W1r, const float* att1, const float* b1,
                     const float* att2, const float* b2,
                     const int* batch, float* pool,
                     u16* XLh, u16* XRh, float* A2, u16* Ahi, u16* Alo,
                     const u16* Wth, const u16* Wtl,
                     const int* cnt, const int* offs, const int* csr_src,
                     hipStream_t st) {
  const int gb = (N + 3) / 4;
  k_lin_small<<<(N + 7) / 8, 256, 0, st>>>(x, W1l, W1r, N, K, XLh, XRh);
  k_gat_gather<2, true><<<gb, 256, 0, st>>>(XLh, XRh, csr_src, offs, cnt, att1, b1, N,
                                            nullptr, Ahi, Alo);
  k_mm_dual<<<dim3((N + 127) / 128, 4), 256, 0, st>>>(Ahi, Alo, Wth, Wtl, XLh, XRh, N);
  k_gat_gather<1, false><<<gb, 256, 0, st>>>(XLh, XRh, csr_src, offs, cnt, att2, b2, N,
                                             A2, nullptr, nullptr);
  k_pool<<<256, 256, 0, st>>>(A2, batch, N, pool);
}

extern "C" void kernel_launch(void* const* d_in, const int* in_sizes, int n_in,
                              void* d_out, int out_size, void* d_ws, size_t ws_size,
                              hipStream_t stream) {
  const float* px = (const float*)d_in[0];
  const float* lx = (const float*)d_in[1];
  const int* pei = (const int*)d_in[2];
  const int* lei = (const int*)d_in[3];
  const int* pb = (const int*)d_in[4];
  const int* lb = (const int*)d_in[5];
  const float* p1_Wl = (const float*)d_in[6];
  const float* p1_Wr = (const float*)d_in[7];
  const float* p1_att = (const float*)d_in[8];
  const float* p1_b = (const float*)d_in[9];
  const float* p2_Wl = (const float*)d_in[10];
  const float* p2_Wr = (const float*)d_in[11];
  const float* p2_att = (const float*)d_in[12];
  const float* p2_b = (const float*)d_in[13];
  const float* l1_Wl = (const float*)d_in[14];
  const float* l1_Wr = (const float*)d_in[15];
  const float* l1_att = (const float*)d_in[16];
  const float* l1_b = (const float*)d_in[17];
  const float* l2_Wl = (const float*)d_in[18];
  const float* l2_Wr = (const float*)d_in[19];
  const float* l2_att = (const float*)d_in[20];
  const float* l2_b = (const float*)d_in[21];
  const float* Wv = (const float*)d_in[26];
  const float* bv = (const float*)d_in[27];
  const float* Wo = (const float*)d_in[28];
  const float* bo = (const float*)d_in[29];
  const float* fc1w = (const float*)d_in[30];
  const float* fc1b = (const float*)d_in[31];
  const float* lng = (const float*)d_in[32];
  const float* lnb = (const float*)d_in[33];
  const float* fc2w = (const float*)d_in[34];
  const float* fc2b = (const float*)d_in[35];

  const int NPn = in_sizes[4];
  const int NLn = in_sizes[5];
  const int EPe = in_sizes[2] / 2;
  const int ELe = in_sizes[3] / 2;
  const int KP = in_sizes[0] / NPn;
  const int KL = in_sizes[1] / NLn;

  const int Nmax = NPn > NLn ? NPn : NLn;
  const int Emax = EPe > ELe ? EPe : ELe;
  size_t NF = (size_t)Nmax * 256;

  u16* XLh = (u16*)d_ws;
  u16* XRh = XLh + NF;
  u16* Ahi = XRh + NF;
  u16* Alo = Ahi + NF;
  float* A2 = (float*)Ahi;  // aliases Ahi+Alo (2*NF u16 == NF f32) after GEMM consumed them
  u16* Wth = Alo + NF;      // 2 sides x 512*256
  u16* Wtl = Wth + 2 * 512 * 256;
  float* PP = (float*)(Wtl + 2 * 512 * 256);
  float* LP = PP + 256 * 256;
  int* cnt = (int*)(LP + 256 * 256);
  int* cur = cnt + 2 * (size_t)Nmax;
  int* offs = cur + 2 * (size_t)Nmax;
  int* bsum = offs + 2 * (size_t)Nmax;
  int* csr = bsum + 512;
  int* cnt_l = cnt + Nmax;
  int* cur_l = cur + Nmax;
  int* offs_l = offs + Nmax;
  int* csr_l = csr + Emax;

  const int nbp = (NPn + 255) / 256;
  const int nbl = (NLn + 255) / 256;

  k_zero2b<<<(2 * Nmax + 255) / 256, 256, 0, stream>>>(cnt, cur, 2 * Nmax);
  k_histb<<<(EPe + ELe + 255) / 256, 256, 0, stream>>>(pei, EPe, lei, ELe, cnt, cnt_l);
  k_scan1b<<<nbp + nbl, 256, 0, stream>>>(cnt, NPn, cnt_l, NLn, nbp, offs, offs_l, bsum);
  k_scan2b<<<2, 256, 0, stream>>>(bsum, nbp, nbl);
  k_scan3b<<<nbp + nbl, 256, 0, stream>>>(offs, NPn, offs_l, NLn, nbp, bsum);
  k_fillb<<<(EPe + ELe + 255) / 256, 256, 0, stream>>>(pei, EPe, lei, ELe, offs, offs_l,
                                                       cur, cur_l, csr, csr_l);
  k_wsplitb<<<1024, 256, 0, stream>>>(p2_Wl, p2_Wr, l2_Wl, l2_Wr,
                                      Wth, Wtl, Wth + 512 * 256, Wtl + 512 * 256);

  run_side(px, KP, NPn, p1_Wl, p1_Wr, p1_att, p1_b, p2_att, p2_b, pb, PP,
           XLh, XRh, A2, Ahi, Alo, Wth, Wtl, cnt, offs, csr, stream);
  run_side(lx, KL, NLn, l1_Wl, l1_Wr, l1_att, l1_b, l2_att, l2_b, lb, LP,
           XLh, XRh, A2, Ahi, Alo, Wth + 512 * 256, Wtl + 512 * 256, cnt_l, offs_l, csr_l,
           stream);

  k_head<<<256, 256, 0, stream>>>(PP, LP, Wv, bv, Wo, bo, fc1w, fc1b, lng, lnb, fc2w, fc2b,
                                  (float*)d_out);
  (void)n_in; (void)out_size; (void)ws_size;
}